// Round 1
// baseline (895.587 us; speedup 1.0000x reference)
//
#include <hip/hip_runtime.h>
#include <hip/hip_fp16.h>

typedef _Float16 f16;
typedef f16 f16x4 __attribute__((ext_vector_type(4)));
typedef f16 f16x8 __attribute__((ext_vector_type(8)));
typedef float f32x4 __attribute__((ext_vector_type(4)));

#define DEVI static __device__ __forceinline__

DEVI void gload_lds16(const void* g, void* l) {
  __builtin_amdgcn_global_load_lds(
      (const __attribute__((address_space(1))) unsigned int*)g,
      (__attribute__((address_space(3))) unsigned int*)l, 16, 0, 0);
}

DEVI float wave_red_sum64(float v) {
#pragma unroll
  for (int m = 1; m < 64; m <<= 1) v += __shfl_xor(v, m, 64);
  return v;
}
DEVI float wave_red_max64(float v) {
#pragma unroll
  for (int m = 1; m < 64; m <<= 1) v = fmaxf(v, __shfl_xor(v, m, 64));
  return v;
}

// ------------------------------ f32 -> f16 cast ------------------------------
__global__ void cvt_f16_kernel(const float* __restrict__ s, f16* __restrict__ d, int n) {
  int i = (blockIdx.x * 256 + threadIdx.x) * 4;
  if (i >= n) return;
  float4 v = *(const float4*)(s + i);
  f16x4 o = {(f16)v.x, (f16)v.y, (f16)v.z, (f16)v.w};
  *(f16x4*)(d + i) = o;
}

// ------------------------------ LayerNorm D=512 ------------------------------
// 4 rows/block, one wave per row. Optional fused residual add (sumout = in+add).
__global__ void ln_kernel(const float* __restrict__ in, const float* __restrict__ add,
                          const float* __restrict__ g, const float* __restrict__ b,
                          float* __restrict__ sumout, float* __restrict__ lnf,
                          f16* __restrict__ lnh) {
  const int row = blockIdx.x * 4 + (threadIdx.x >> 6);
  const int lane = threadIdx.x & 63;
  const long base = (long)row * 512;
  const int c0 = lane * 4, c1 = 256 + lane * 4;
  float4 a0 = *(const float4*)(in + base + c0);
  float4 a1 = *(const float4*)(in + base + c1);
  if (add) {
    float4 d0 = *(const float4*)(add + base + c0);
    float4 d1 = *(const float4*)(add + base + c1);
    a0.x += d0.x; a0.y += d0.y; a0.z += d0.z; a0.w += d0.w;
    a1.x += d1.x; a1.y += d1.y; a1.z += d1.z; a1.w += d1.w;
  }
  if (sumout) {
    *(float4*)(sumout + base + c0) = a0;
    *(float4*)(sumout + base + c1) = a1;
  }
  float v[8] = {a0.x, a0.y, a0.z, a0.w, a1.x, a1.y, a1.z, a1.w};
  float s = 0.f;
#pragma unroll
  for (int k = 0; k < 8; k++) s += v[k];
  s = wave_red_sum64(s);
  const float mean = s * (1.f / 512.f);
  float vs = 0.f;
#pragma unroll
  for (int k = 0; k < 8; k++) { float d = v[k] - mean; vs += d * d; }
  vs = wave_red_sum64(vs);
  const float rstd = rsqrtf(vs * (1.f / 512.f) + 1e-5f);
  float4 g0 = *(const float4*)(g + c0), g1 = *(const float4*)(g + c1);
  float4 p0 = *(const float4*)(b + c0), p1 = *(const float4*)(b + c1);
  const float gg[8] = {g0.x, g0.y, g0.z, g0.w, g1.x, g1.y, g1.z, g1.w};
  const float bv[8] = {p0.x, p0.y, p0.z, p0.w, p1.x, p1.y, p1.z, p1.w};
  float y[8];
#pragma unroll
  for (int k = 0; k < 8; k++) y[k] = (v[k] - mean) * rstd * gg[k] + bv[k];
  if (lnf) {
    float4 o0 = {y[0], y[1], y[2], y[3]}, o1 = {y[4], y[5], y[6], y[7]};
    *(float4*)(lnf + base + c0) = o0;
    *(float4*)(lnf + base + c1) = o1;
  }
  if (lnh) {
    f16x4 o0 = {(f16)y[0], (f16)y[1], (f16)y[2], (f16)y[3]};
    f16x4 o1 = {(f16)y[4], (f16)y[5], (f16)y[6], (f16)y[7]};
    *(f16x4*)(lnh + base + c0) = o0;
    *(f16x4*)(lnh + base + c1) = o1;
  }
}

// ------------------------------ generic fp16 MFMA GEMM, C = A(MxK) * W(NxK)^T
// 128x128 tile, BK=64, 4 waves (2x2 of 64x64), 16x16x32 f16 MFMA.
// LDS xor-swizzle: linear global_load_lds dest + inverse-swizzled SOURCE + swizzled read.
enum { EPI_HEADS = 0, EPI_VT = 1, EPI_SCORES = 2, EPI_PV = 3, EPI_WO = 4, EPI_GELU = 5, EPI_OUT = 6 };

template <int EPI>
__launch_bounds__(256, 1) __global__
void gemm_bt(const f16* __restrict__ A, const f16* __restrict__ W, int lda, int ldw,
             long Az, long Wz, void* __restrict__ dst, const float* __restrict__ bias,
             const float* __restrict__ resid, int K, float scale, int zofs) {
  if (EPI == EPI_SCORES && blockIdx.x > blockIdx.y) return;  // causal tile skip
  __shared__ f16 lA[128 * 64];
  __shared__ f16 lB[128 * 64];
  const int tid = threadIdx.x;
  const int wave = tid >> 6, lane = tid & 63;
  const int z = blockIdx.z;
  const f16* Ab = A + (long)z * Az + (long)blockIdx.y * 128 * lda;
  const f16* Wb = W + (long)z * Wz + (long)blockIdx.x * 128 * ldw;

  f32x4 acc[4][4];
#pragma unroll
  for (int a = 0; a < 4; a++)
#pragma unroll
    for (int q = 0; q < 4; q++) acc[a][q] = (f32x4){0.f, 0.f, 0.f, 0.f};

  int srow[4], scol[4];
#pragma unroll
  for (int i = 0; i < 4; i++) {
    int c = i * 256 + tid;   // 16B chunk index in 16KB tile
    int row = c >> 3;        // 8 chunks per 128B row
    int colb = (c & 7) << 4; // byte col in row
    srow[i] = row;
    scol[i] = (colb ^ ((row & 7) << 4)) >> 1;  // pre-swizzled source elem col
  }

  for (int k0 = 0; k0 < K; k0 += 64) {
    __syncthreads();
#pragma unroll
    for (int i = 0; i < 4; i++) {
      const int le = (i * 256 + wave * 64) * 8;  // wave-uniform LDS elem base
      gload_lds16(Ab + (long)srow[i] * lda + k0 + scol[i], lA + le);
      gload_lds16(Wb + (long)srow[i] * ldw + k0 + scol[i], lB + le);
    }
    __syncthreads();  // drains vmcnt(0) too
    const int wm = (wave >> 1) * 64, wn = (wave & 1) * 64;
#pragma unroll
    for (int km = 0; km < 2; km++) {
      const int kb = km * 64 + ((lane >> 4) << 4);
      f16x8 af[4], bfv[4];
#pragma unroll
      for (int mf = 0; mf < 4; mf++) {
        int r = wm + mf * 16 + (lane & 15);
        af[mf] = *(const f16x8*)((const char*)lA + r * 128 + (kb ^ ((r & 7) << 4)));
      }
#pragma unroll
      for (int nf = 0; nf < 4; nf++) {
        int r = wn + nf * 16 + (lane & 15);
        bfv[nf] = *(const f16x8*)((const char*)lB + r * 128 + (kb ^ ((r & 7) << 4)));
      }
#pragma unroll
      for (int mf = 0; mf < 4; mf++)
#pragma unroll
        for (int nf = 0; nf < 4; nf++)
          acc[mf][nf] = __builtin_amdgcn_mfma_f32_16x16x32_f16(af[mf], bfv[nf], acc[mf][nf], 0, 0, 0);
    }
  }

  // epilogue: C elem (mf,nf,j): row=(lane>>4)*4+j, col=lane&15 within 16x16 frag
  const int wm = (wave >> 1) * 64, wn = (wave & 1) * 64;
  const int rbase = blockIdx.y * 128 + wm + ((lane >> 4) << 2);
  const int cbase = blockIdx.x * 128 + wn + (lane & 15);
#pragma unroll
  for (int mf = 0; mf < 4; mf++)
#pragma unroll
    for (int nf = 0; nf < 4; nf++)
#pragma unroll
      for (int j = 0; j < 4; j++) {
        const int m = rbase + mf * 16 + j;
        const int n = cbase + nf * 16;
        const float v = acc[mf][nf][j];
        if (EPI == EPI_HEADS) {
          ((f16*)dst)[(long)((m >> 9) * 8 + (n >> 6)) * 32768 + (m & 511) * 64 + (n & 63)] = (f16)v;
        } else if (EPI == EPI_VT) {
          ((f16*)dst)[(long)((m >> 9) * 8 + (n >> 6)) * 32768 + (n & 63) * 512 + (m & 511)] = (f16)v;
        } else if (EPI == EPI_SCORES) {
          ((float*)dst)[(long)z * 262144 + (long)m * 512 + n] = v * scale;
        } else if (EPI == EPI_PV) {
          if (n < 64) {
            const int hh = z + zofs;
            ((f16*)dst)[(long)((hh >> 3) * 512 + m) * 512 + (hh & 7) * 64 + n] = (f16)v;
          }
        } else if (EPI == EPI_WO) {
          ((float*)dst)[(long)m * 512 + n] = v + resid[(long)m * 512 + n];
        } else if (EPI == EPI_GELU) {
          const float u = v + bias[n];
          ((f16*)dst)[(long)m * 2048 + n] = (f16)(0.5f * u * (1.f + erff(u * 0.70710678118f)));
        } else {  // EPI_OUT
          ((float*)dst)[(long)m * 512 + n] = v + bias[n] + resid[(long)m * 512 + n];
        }
      }
}

// ------------------------------ softmax-diff-L1, one wave per row ------------
__global__ void softmax_diff_kernel(const float* __restrict__ S1, const float* __restrict__ S2,
                                    const float* __restrict__ lamlog, f16* __restrict__ attn,
                                    int zofs) {
  const int rid = blockIdx.x * 4 + (threadIdx.x >> 6);
  const int lane = threadIdx.x & 63;
  const int z = rid >> 9, i = rid & 511;
  const float lam = 1.f / (1.f + __expf(-lamlog[(z + zofs) & 7]));
  const long base = (long)z * 262144 + (long)i * 512;
  const int c0 = lane * 4, c1 = 256 + lane * 4;
  float4 xa = *(const float4*)(S1 + base + c0);
  float4 xb = *(const float4*)(S1 + base + c1);
  float4 ya = *(const float4*)(S2 + base + c0);
  float4 yb = *(const float4*)(S2 + base + c1);
  float s1v[8] = {xa.x, xa.y, xa.z, xa.w, xb.x, xb.y, xb.z, xb.w};
  float s2v[8] = {ya.x, ya.y, ya.z, ya.w, yb.x, yb.y, yb.z, yb.w};
  int cols[8];
#pragma unroll
  for (int k = 0; k < 8; k++) cols[k] = (k < 4) ? (c0 + k) : (c1 + k - 4);
  float m1 = -3.0e38f, m2 = -3.0e38f;
#pragma unroll
  for (int k = 0; k < 8; k++)
    if (cols[k] <= i) { m1 = fmaxf(m1, s1v[k]); m2 = fmaxf(m2, s2v[k]); }
  m1 = wave_red_max64(m1);
  m2 = wave_red_max64(m2);
  float z1 = 0.f, z2 = 0.f, e1[8], e2[8];
#pragma unroll
  for (int k = 0; k < 8; k++) {
    const bool valid = cols[k] <= i;
    e1[k] = valid ? __expf(s1v[k] - m1) : 0.f;
    e2[k] = valid ? __expf(s2v[k] - m2) : 0.f;
    z1 += e1[k]; z2 += e2[k];
  }
  z1 = wave_red_sum64(z1);
  z2 = wave_red_sum64(z2);
  const float r1 = 1.f / z1, r2 = lam / z2;
  float p[8], l1 = 0.f;
#pragma unroll
  for (int k = 0; k < 8; k++) { p[k] = e1[k] * r1 - e2[k] * r2; l1 += fabsf(p[k]); }
  l1 = wave_red_sum64(l1);
  const float rn = 1.f / fmaxf(l1, 1e-6f);
  f16x4 o0 = {(f16)(p[0] * rn), (f16)(p[1] * rn), (f16)(p[2] * rn), (f16)(p[3] * rn)};
  f16x4 o1 = {(f16)(p[4] * rn), (f16)(p[5] * rn), (f16)(p[6] * rn), (f16)(p[7] * rn)};
  *(f16x4*)(attn + base + c0) = o0;
  *(f16x4*)(attn + base + c1) = o1;
}

// ------------------------------ eta (inner_lr * lrm2) precompute -------------
// The nov/ema/lrm chain depends only on x2, not fw -> computed once, reused by
// both the fast and fallback TTT paths.
__global__ void eta_kernel(const float* __restrict__ x2, const float* __restrict__ loglr,
                           float* __restrict__ eta) {
  const int b = blockIdx.x;
  const int tid = threadIdx.x;  // 512
  const int wave = tid >> 6, lane = tid & 63;
  __shared__ float part[512 * 8];
  const float* xb = x2 + (long)b * 262144;
  float ema = 0.f;
  for (int t = 0; t < 512; t++) {
    const float x = xb[t * 512 + tid];
    float d = fabsf(x - ema);          // uses pre-update ema
    ema = fmaf(0.95f, ema, 0.05f * x);
    d = wave_red_sum64(d);
    if (lane == 0) part[t * 8 + wave] = d;
  }
  __syncthreads();
  if (tid == 0) {
    float ilr = expf(loglr[0]);
    ilr = fminf(fmaxf(ilr, 1e-5f), 1.f);
    float lrm = 1.f;
    for (int t = 0; t < 512; t++) {
      float nov = 0.f;
      for (int w = 0; w < 8; w++) nov += part[t * 8 + w];
      nov *= (1.f / 512.f);
      const float ls = fminf(fmaxf(1.f + 3.f * nov, 0.5f), 3.f);
      lrm = fmaf(0.95f, lrm, 0.05f * ls);
      eta[b * 512 + t] = ilr * lrm;
    }
  }
}

// ------------------------------ TTT fast path (speculative: clip never fires)
// 128 blocks (64/batch), 8 fw rows/block in registers. No inter-block sync.
// Logs per-step ||fw2||^2 partials for the verify kernel.
__launch_bounds__(256, 1) __global__
void ttt_fast_kernel(const float* __restrict__ x2, const float* __restrict__ base_w,
                     const float* __restrict__ tbias, const float* __restrict__ eta,
                     float* __restrict__ ys, float* __restrict__ normpart) {
  const int blk = blockIdx.x;
  const int b = blk >> 6, blkb = blk & 63;
  const int r0 = blkb * 8;
  const int tid = threadIdx.x;
  const int cg = tid & 31;             // 32 threads per row, 16 cols each
  const int row = r0 + (tid >> 5);
  const int wave = tid >> 6, lane = tid & 63;
  const float* xb = x2 + (long)b * 262144;

  float fw[16], mom[16];
  {
    const float* bp = base_w + (long)row * 512 + cg * 16;
#pragma unroll
    for (int i = 0; i < 4; i++) {
      float4 t4 = *(const float4*)(bp + i * 4);
      fw[i * 4 + 0] = t4.x; fw[i * 4 + 1] = t4.y; fw[i * 4 + 2] = t4.z; fw[i * 4 + 3] = t4.w;
    }
  }
#pragma unroll
  for (int i = 0; i < 16; i++) mom[i] = 0.f;
  const float biasr = tbias[row];

  __shared__ float xs[2][512];
  __shared__ float nsq_s[2][4];

  if (wave < 2) gload_lds16(xb + (wave * 64 + lane) * 4, &xs[0][wave * 256]);
  __syncthreads();

  for (int t = 0; t < 512; t++) {
    const int p = t & 1;
    if (t < 511 && wave < 2)
      gload_lds16(xb + (long)(t + 1) * 512 + (wave * 64 + lane) * 4, &xs[1 - p][wave * 256]);
    const float eta_t = eta[b * 512 + t];
    float xr[16];
#pragma unroll
    for (int i = 0; i < 4; i++) {
      float4 t4 = *(const float4*)(&xs[p][cg * 16 + i * 4]);
      xr[i * 4 + 0] = t4.x; xr[i * 4 + 1] = t4.y; xr[i * 4 + 2] = t4.z; xr[i * 4 + 3] = t4.w;
    }
    float zp = 0.f;
#pragma unroll
    for (int i = 0; i < 16; i++) zp = fmaf(fw[i], xr[i], zp);
#pragma unroll
    for (int m = 1; m < 32; m <<= 1) zp += __shfl_xor(zp, m, 64);
    const float y = zp + biasr;
    if (cg == 0) ys[((long)b * 512 + t) * 512 + row] = y;
    const float errv = (y - xs[p][row]) * (1.f / 512.f);
    const float c1 = 0.1f * errv;  // (1-MOM_BETA)*err
    float nsq = 0.f;
#pragma unroll
    for (int i = 0; i < 16; i++) {
      mom[i] = fmaf(0.9f, mom[i], c1 * xr[i]);
      fw[i] = fmaf(-eta_t, mom[i], fw[i]);
      nsq = fmaf(fw[i], fw[i], nsq);
    }
    nsq = wave_red_sum64(nsq);
    if (lane == 0) nsq_s[p][wave] = nsq;
    __syncthreads();  // also drains x prefetch (vmcnt 0)
    if (tid == 0)
      normpart[((long)b * 512 + t) * 64 + blkb] =
          nsq_s[p][0] + nsq_s[p][1] + nsq_s[p][2] + nsq_s[p][3];
  }
}

// ------------------------------ verify: did any step exceed the norm clip? ---
__global__ void verify_kernel(const float* __restrict__ normpart, int* __restrict__ flag) {
  const int t = threadIdx.x;  // 512
  int bad = 0;
  for (int b = 0; b < 2; b++) {
    float s = 0.f;
    for (int k = 0; k < 64; k++) s += normpart[((long)b * 512 + t) * 64 + k];
    if (s > 1024.f) bad = 1;  // norm > 32
  }
  __shared__ int anyb;
  if (t == 0) anyb = 0;
  __syncthreads();
  if (bad) atomicOr(&anyb, 1);
  __syncthreads();
  if (t == 0) flag[0] = anyb;
}

// ------------------------------ TTT fallback (exact, with clip) --------------
// Correctness-only path; executes only when verify fired (never, for this input).
__launch_bounds__(1024, 1) __global__
void ttt_fallback_kernel(const int* __restrict__ flag, const float* __restrict__ x2,
                         const float* __restrict__ base_w, const float* __restrict__ tbias,
                         const float* __restrict__ eta, float* __restrict__ ys,
                         float* __restrict__ fwg, float* __restrict__ momg) {
  if (flag[0] == 0) return;
  const int b = blockIdx.x;
  const int tid = threadIdx.x;  // 1024
  const int wave = tid >> 6, lane = tid & 63;
  float* fw = fwg + (long)b * 262144;
  float* mm = momg + (long)b * 262144;
  for (int e = tid; e < 262144; e += 1024) { fw[e] = base_w[e]; mm[e] = 0.f; }
  __shared__ float xs[512], errs[512], red[16];
  const float* xb = x2 + (long)b * 262144;
  for (int t = 0; t < 512; t++) {
    __syncthreads();
    if (tid < 512) xs[tid] = xb[t * 512 + tid];
    __syncthreads();
    if (tid < 512) {
      float acc = 0.f;
      for (int c = 0; c < 512; c++) acc = fmaf(fw[(long)tid * 512 + c], xs[c], acc);
      const float y = acc + tbias[tid];
      ys[((long)b * 512 + t) * 512 + tid] = y;
      errs[tid] = (y - xs[tid]) * (1.f / 512.f);
    }
    __syncthreads();
    const float eta_t = eta[b * 512 + t];
    float nsq = 0.f;
    for (int e = tid; e < 262144; e += 1024) {
      const int r = e >> 9, c = e & 511;
      const float m2 = fmaf(0.9f, mm[e], 0.1f * errs[r] * xs[c]);
      mm[e] = m2;
      const float f2 = fmaf(-eta_t, m2, fw[e]);
      fw[e] = f2;
      nsq = fmaf(f2, f2, nsq);
    }
    nsq = wave_red_sum64(nsq);
    if (lane == 0) red[wave] = nsq;
    __syncthreads();
    if (tid == 0) {
      float s = 0.f;
      for (int w = 0; w < 16; w++) s += red[w];
      red[0] = s;
    }
    __syncthreads();
    const float norm = fmaxf(sqrtf(red[0]), 1e-6f);
    const float sc = fminf(32.f / norm, 1.f);
    if (sc < 1.f)
      for (int e = tid; e < 262144; e += 1024) fw[e] *= sc;
  }
}

// ------------------------------ host launch ------------------------------
extern "C" void kernel_launch(void* const* d_in, const int* in_sizes, int n_in,
                              void* d_out, int out_size, void* d_ws, size_t ws_size,
                              hipStream_t stream) {
  (void)in_sizes; (void)n_in; (void)out_size;
  const float* x      = (const float*)d_in[0];
  const float* Wq     = (const float*)d_in[1];
  const float* Wk1    = (const float*)d_in[2];
  const float* Wk2    = (const float*)d_in[3];
  const float* Wv     = (const float*)d_in[4];
  const float* Wo     = (const float*)d_in[5];
  const float* lamlog = (const float*)d_in[6];
  const float* ln1g   = (const float*)d_in[7];
  const float* ln1b   = (const float*)d_in[8];
  const float* basew  = (const float*)d_in[9];
  const float* tttb   = (const float*)d_in[10];
  const float* loglr  = (const float*)d_in[11];
  const float* ln2g   = (const float*)d_in[12];
  const float* ln2b   = (const float*)d_in[13];
  const float* W1     = (const float*)d_in[14];
  const float* b1     = (const float*)d_in[15];
  const float* W2     = (const float*)d_in[16];
  const float* b2     = (const float*)d_in[17];
  const float* ln3g   = (const float*)d_in[18];
  const float* ln3b   = (const float*)d_in[19];
  float* out = (float*)d_out;

  char* ws = (char*)d_ws;
  size_t off = 0;
  auto alloc = [&](size_t bytes) {
    size_t o = off;
    off += (bytes + 255) & ~(size_t)255;
    return o;
  };
  f16* WqH   = (f16*)(ws + alloc(262144 * 2));
  f16* Wk1H  = (f16*)(ws + alloc(262144 * 2));
  f16* Wk2H  = (f16*)(ws + alloc(262144 * 2));
  f16* WvH   = (f16*)(ws + alloc(262144 * 2));
  f16* WoH   = (f16*)(ws + alloc(262144 * 2));
  f16* W1H   = (f16*)(ws + alloc(1048576 * 2));
  f16* W2H   = (f16*)(ws + alloc(1048576 * 2));
  f16* xlnH  = (f16*)(ws + alloc(524288 * 2));
  f16* qh    = (f16*)(ws + alloc(524288 * 2));
  f16* k1h   = (f16*)(ws + alloc(524288 * 2));
  f16* k2h   = (f16*)(ws + alloc(524288 * 2));
  f16* vTh   = (f16*)(ws + alloc(524288 * 2));
  f16* obtd  = (f16*)(ws + alloc(524288 * 2));  // placed right after vTh (PV over-read pad)
  f16* x3h   = (f16*)(ws + alloc(524288 * 2));
  f16* zh    = (f16*)(ws + alloc(2097152 * 2));
  float* h1  = (float*)(ws + alloc(524288 * 4));
  float* x2  = (float*)(ws + alloc(524288 * 4));
  float* ysb = (float*)(ws + alloc(524288 * 4));
  float* h2  = (float*)(ws + alloc(524288 * 4));
  float* eta = (float*)(ws + alloc(1024 * 4));
  float* npt = (float*)(ws + alloc(2 * 512 * 64 * 4));
  int* flag  = (int*)(ws + alloc(256));
  float* fwfb  = (float*)(ws + alloc(524288 * 4));
  float* momfb = (float*)(ws + alloc(524288 * 4));

  int hc = 16;  // heads per attention chunk, shrink if ws is small
  while (hc > 1 && off + (size_t)hc * (262144ull * 4 * 2 + 262144ull * 2) > ws_size) hc >>= 1;
  float* S1  = (float*)(ws + alloc((size_t)hc * 262144 * 4));
  float* S2  = (float*)(ws + alloc((size_t)hc * 262144 * 4));
  f16* attnb = (f16*)(ws + alloc((size_t)hc * 262144 * 2));

  // ---- weight casts to fp16 ----
  cvt_f16_kernel<<<256, 256, 0, stream>>>(Wq, WqH, 262144);
  cvt_f16_kernel<<<256, 256, 0, stream>>>(Wk1, Wk1H, 262144);
  cvt_f16_kernel<<<256, 256, 0, stream>>>(Wk2, Wk2H, 262144);
  cvt_f16_kernel<<<256, 256, 0, stream>>>(Wv, WvH, 262144);
  cvt_f16_kernel<<<256, 256, 0, stream>>>(Wo, WoH, 262144);
  cvt_f16_kernel<<<1024, 256, 0, stream>>>(W1, W1H, 1048576);
  cvt_f16_kernel<<<1024, 256, 0, stream>>>(W2, W2H, 1048576);

  // ---- LN1 -> xln (fp16) ----
  ln_kernel<<<256, 256, 0, stream>>>(x, nullptr, ln1g, ln1b, nullptr, nullptr, xlnH);

  // ---- q/k1/k2 projections ([B,H,T,64]), v transposed ([B,H,64,T]) ----
  gemm_bt<EPI_HEADS><<<dim3(4, 8, 1), 256, 0, stream>>>(xlnH, WqH, 512, 512, 0, 0, qh, nullptr, nullptr, 512, 1.f, 0);
  gemm_bt<EPI_HEADS><<<dim3(4, 8, 1), 256, 0, stream>>>(xlnH, Wk1H, 512, 512, 0, 0, k1h, nullptr, nullptr, 512, 1.f, 0);
  gemm_bt<EPI_HEADS><<<dim3(4, 8, 1), 256, 0, stream>>>(xlnH, Wk2H, 512, 512, 0, 0, k2h, nullptr, nullptr, 512, 1.f, 0);
  gemm_bt<EPI_VT><<<dim3(4, 8, 1), 256, 0, stream>>>(xlnH, WvH, 512, 512, 0, 0, vTh, nullptr, nullptr, 512, 1.f, 0);

  // ---- attention: scores -> softmax-diff-L1 -> PV, chunked over heads ----
  const int nc = 16 / hc;
  for (int c = 0; c < nc; c++) {
    const int cs = c * hc;
    gemm_bt<EPI_SCORES><<<dim3(4, 4, hc), 256, 0, stream>>>(
        qh + (long)cs * 32768, k1h + (long)cs * 32768, 64, 64, 32768, 32768, S1,
        nullptr, nullptr, 64, 0.125f, 0);
    gemm_bt<EPI_SCORES><<<dim3(4, 4, hc), 256, 0, stream>>>(
        qh + (long)cs * 32768, k2h + (long)cs * 32768, 64, 64, 32768, 32768, S2,
        nullptr, nullptr, 64, 0.125f, 0);
    softmax_diff_kernel<<<hc * 128, 256, 0, stream>>>(S1, S2, lamlog, attnb, cs);
    gemm_bt<EPI_PV><<<dim3(1, 4, hc), 256, 0, stream>>>(
        attnb, vTh + (long)cs * 32768, 512, 512, 262144, 32768, obtd,
        nullptr, nullptr, 512, 1.f, cs);
  }

  // ---- Wo projection + residual -> h1 ----
  gemm_bt<EPI_WO><<<dim3(4, 8, 1), 256, 0, stream>>>(obtd, WoH, 512, 512, 0, 0, h1, nullptr, x, 512, 1.f, 0);

  // ---- LN2 -> x2 (f32) ----
  ln_kernel<<<256, 256, 0, stream>>>(h1, nullptr, ln2g, ln2b, nullptr, x2, nullptr);

  // ---- TTT: eta precompute, speculative scan, verify, (dead) fallback ----
  eta_kernel<<<2, 512, 0, stream>>>(x2, loglr, eta);
  ttt_fast_kernel<<<128, 256, 0, stream>>>(x2, basew, tttb, eta, ysb, npt);
  verify_kernel<<<1, 512, 0, stream>>>(npt, flag);
  ttt_fallback_kernel<<<2, 1024, 0, stream>>>(flag, x2, basew, tttb, eta, ysb, fwfb, momfb);

  // ---- h2 = h1 + ys ; LN3 -> x3 (fp16) ----
  ln_kernel<<<256, 256, 0, stream>>>(h1, ysb, ln3g, ln3b, h2, nullptr, x3h);

  // ---- FFN ----
  gemm_bt<EPI_GELU><<<dim3(16, 8, 1), 256, 0, stream>>>(x3h, W1H, 512, 512, 0, 0, zh, b1, nullptr, 512, 1.f, 0);
  gemm_bt<EPI_OUT><<<dim3(4, 8, 1), 256, 0, stream>>>(zh, W2H, 2048, 2048, 0, 0, out, b2, h2, 2048, 1.f, 0);
}

// Round 2
// 740.854 us; speedup vs baseline: 1.2089x; 1.2089x over previous
//
#include <hip/hip_runtime.h>
#include <hip/hip_fp16.h>

typedef _Float16 f16;
typedef f16 f16x4 __attribute__((ext_vector_type(4)));
typedef f16 f16x8 __attribute__((ext_vector_type(8)));
typedef float f32x4 __attribute__((ext_vector_type(4)));

#define DEVI static __device__ __forceinline__

DEVI void gload_lds16(const void* g, void* l) {
  __builtin_amdgcn_global_load_lds(
      (const __attribute__((address_space(1))) unsigned int*)g,
      (__attribute__((address_space(3))) unsigned int*)l, 16, 0, 0);
}

DEVI float wave_red_sum64(float v) {
#pragma unroll
  for (int m = 1; m < 64; m <<= 1) v += __shfl_xor(v, m, 64);
  return v;
}
DEVI float wave_red_max64(float v) {
#pragma unroll
  for (int m = 1; m < 64; m <<= 1) v = fmaxf(v, __shfl_xor(v, m, 64));
  return v;
}

// ---- DPP butterfly helpers (VALU-only cross-lane adds) ----
template <int CTRL>
DEVI float dpp_addf(float v) {
  int s = __builtin_amdgcn_update_dpp(0, __float_as_int(v), CTRL, 0xF, 0xF, true);
  return v + __int_as_float(s);
}
DEVI float swz_add16(float v) {  // += lane^16 partner (bit-mode xor16)
  int s = __builtin_amdgcn_ds_swizzle(__float_as_int(v), 0x401F);
  return v + __int_as_float(s);
}
DEVI float allred32(float v) {   // allreduce within 32-lane groups
  v = dpp_addf<0xB1>(v);    // xor1  (quad_perm 1,0,3,2)
  v = dpp_addf<0x4E>(v);    // xor2  (quad_perm 2,3,0,1)
  v = dpp_addf<0x141>(v);   // xor4  via row_half_mirror (uniform bits0-1)
  v = dpp_addf<0x140>(v);   // xor8  via row_mirror      (uniform bits0-2)
  return swz_add16(v);      // xor16
}
DEVI float red16g(float v) {     // reduce within 16-lane groups
  v = dpp_addf<0xB1>(v);
  v = dpp_addf<0x4E>(v);
  v = dpp_addf<0x141>(v);
  v = dpp_addf<0x140>(v);
  return v;
}

// ------------------------------ f32 -> f16 cast ------------------------------
__global__ void cvt_f16_kernel(const float* __restrict__ s, f16* __restrict__ d, int n) {
  int i = (blockIdx.x * 256 + threadIdx.x) * 4;
  if (i >= n) return;
  float4 v = *(const float4*)(s + i);
  f16x4 o = {(f16)v.x, (f16)v.y, (f16)v.z, (f16)v.w};
  *(f16x4*)(d + i) = o;
}

// ------------------------------ LayerNorm D=512 ------------------------------
__global__ void ln_kernel(const float* __restrict__ in, const float* __restrict__ add,
                          const float* __restrict__ g, const float* __restrict__ b,
                          float* __restrict__ sumout, float* __restrict__ lnf,
                          f16* __restrict__ lnh) {
  const int row = blockIdx.x * 4 + (threadIdx.x >> 6);
  const int lane = threadIdx.x & 63;
  const long base = (long)row * 512;
  const int c0 = lane * 4, c1 = 256 + lane * 4;
  float4 a0 = *(const float4*)(in + base + c0);
  float4 a1 = *(const float4*)(in + base + c1);
  if (add) {
    float4 d0 = *(const float4*)(add + base + c0);
    float4 d1 = *(const float4*)(add + base + c1);
    a0.x += d0.x; a0.y += d0.y; a0.z += d0.z; a0.w += d0.w;
    a1.x += d1.x; a1.y += d1.y; a1.z += d1.z; a1.w += d1.w;
  }
  if (sumout) {
    *(float4*)(sumout + base + c0) = a0;
    *(float4*)(sumout + base + c1) = a1;
  }
  float v[8] = {a0.x, a0.y, a0.z, a0.w, a1.x, a1.y, a1.z, a1.w};
  float s = 0.f;
#pragma unroll
  for (int k = 0; k < 8; k++) s += v[k];
  s = wave_red_sum64(s);
  const float mean = s * (1.f / 512.f);
  float vs = 0.f;
#pragma unroll
  for (int k = 0; k < 8; k++) { float d = v[k] - mean; vs += d * d; }
  vs = wave_red_sum64(vs);
  const float rstd = rsqrtf(vs * (1.f / 512.f) + 1e-5f);
  float4 g0 = *(const float4*)(g + c0), g1 = *(const float4*)(g + c1);
  float4 p0 = *(const float4*)(b + c0), p1 = *(const float4*)(b + c1);
  const float gg[8] = {g0.x, g0.y, g0.z, g0.w, g1.x, g1.y, g1.z, g1.w};
  const float bv[8] = {p0.x, p0.y, p0.z, p0.w, p1.x, p1.y, p1.z, p1.w};
  float y[8];
#pragma unroll
  for (int k = 0; k < 8; k++) y[k] = (v[k] - mean) * rstd * gg[k] + bv[k];
  if (lnf) {
    float4 o0 = {y[0], y[1], y[2], y[3]}, o1 = {y[4], y[5], y[6], y[7]};
    *(float4*)(lnf + base + c0) = o0;
    *(float4*)(lnf + base + c1) = o1;
  }
  if (lnh) {
    f16x4 o0 = {(f16)y[0], (f16)y[1], (f16)y[2], (f16)y[3]};
    f16x4 o1 = {(f16)y[4], (f16)y[5], (f16)y[6], (f16)y[7]};
    *(f16x4*)(lnh + base + c0) = o0;
    *(f16x4*)(lnh + base + c1) = o1;
  }
}

// ------------------------------ generic fp16 MFMA GEMM, C = A(MxK) * W(NxK)^T
enum { EPI_HEADS = 0, EPI_VT = 1, EPI_SCORES = 2, EPI_PV = 3, EPI_WO = 4, EPI_GELU = 5, EPI_OUT = 6 };

template <int EPI>
__launch_bounds__(256, 1) __global__
void gemm_bt(const f16* __restrict__ A, const f16* __restrict__ W, int lda, int ldw,
             long Az, long Wz, void* __restrict__ dst, const float* __restrict__ bias,
             const float* __restrict__ resid, int K, float scale, int zofs) {
  if (EPI == EPI_SCORES && blockIdx.x > blockIdx.y) return;  // causal tile skip
  __shared__ f16 lA[128 * 64];
  __shared__ f16 lB[128 * 64];
  const int tid = threadIdx.x;
  const int wave = tid >> 6, lane = tid & 63;
  const int z = blockIdx.z;
  const f16* Ab = A + (long)z * Az + (long)blockIdx.y * 128 * lda;
  const f16* Wb = W + (long)z * Wz + (long)blockIdx.x * 128 * ldw;

  f32x4 acc[4][4];
#pragma unroll
  for (int a = 0; a < 4; a++)
#pragma unroll
    for (int q = 0; q < 4; q++) acc[a][q] = (f32x4){0.f, 0.f, 0.f, 0.f};

  int srow[4], scol[4];
#pragma unroll
  for (int i = 0; i < 4; i++) {
    int c = i * 256 + tid;
    int row = c >> 3;
    int colb = (c & 7) << 4;
    srow[i] = row;
    scol[i] = (colb ^ ((row & 7) << 4)) >> 1;
  }

  for (int k0 = 0; k0 < K; k0 += 64) {
    __syncthreads();
#pragma unroll
    for (int i = 0; i < 4; i++) {
      const int le = (i * 256 + wave * 64) * 8;
      gload_lds16(Ab + (long)srow[i] * lda + k0 + scol[i], lA + le);
      gload_lds16(Wb + (long)srow[i] * ldw + k0 + scol[i], lB + le);
    }
    __syncthreads();
    const int wm = (wave >> 1) * 64, wn = (wave & 1) * 64;
#pragma unroll
    for (int km = 0; km < 2; km++) {
      const int kb = km * 64 + ((lane >> 4) << 4);
      f16x8 af[4], bfv[4];
#pragma unroll
      for (int mf = 0; mf < 4; mf++) {
        int r = wm + mf * 16 + (lane & 15);
        af[mf] = *(const f16x8*)((const char*)lA + r * 128 + (kb ^ ((r & 7) << 4)));
      }
#pragma unroll
      for (int nf = 0; nf < 4; nf++) {
        int r = wn + nf * 16 + (lane & 15);
        bfv[nf] = *(const f16x8*)((const char*)lB + r * 128 + (kb ^ ((r & 7) << 4)));
      }
#pragma unroll
      for (int mf = 0; mf < 4; mf++)
#pragma unroll
        for (int nf = 0; nf < 4; nf++)
          acc[mf][nf] = __builtin_amdgcn_mfma_f32_16x16x32_f16(af[mf], bfv[nf], acc[mf][nf], 0, 0, 0);
    }
  }

  const int wm = (wave >> 1) * 64, wn = (wave & 1) * 64;
  const int rbase = blockIdx.y * 128 + wm + ((lane >> 4) << 2);
  const int cbase = blockIdx.x * 128 + wn + (lane & 15);
#pragma unroll
  for (int mf = 0; mf < 4; mf++)
#pragma unroll
    for (int nf = 0; nf < 4; nf++)
#pragma unroll
      for (int j = 0; j < 4; j++) {
        const int m = rbase + mf * 16 + j;
        const int n = cbase + nf * 16;
        const float v = acc[mf][nf][j];
        if (EPI == EPI_HEADS) {
          ((f16*)dst)[(long)((m >> 9) * 8 + (n >> 6)) * 32768 + (m & 511) * 64 + (n & 63)] = (f16)v;
        } else if (EPI == EPI_VT) {
          ((f16*)dst)[(long)((m >> 9) * 8 + (n >> 6)) * 32768 + (n & 63) * 512 + (m & 511)] = (f16)v;
        } else if (EPI == EPI_SCORES) {
          ((float*)dst)[(long)z * 262144 + (long)m * 512 + n] = v * scale;
        } else if (EPI == EPI_PV) {
          if (n < 64) {
            const int hh = z + zofs;
            ((f16*)dst)[(long)((hh >> 3) * 512 + m) * 512 + (hh & 7) * 64 + n] = (f16)v;
          }
        } else if (EPI == EPI_WO) {
          ((float*)dst)[(long)m * 512 + n] = v + resid[(long)m * 512 + n];
        } else if (EPI == EPI_GELU) {
          const float u = v + bias[n];
          ((f16*)dst)[(long)m * 2048 + n] = (f16)(0.5f * u * (1.f + erff(u * 0.70710678118f)));
        } else {
          ((float*)dst)[(long)m * 512 + n] = v + bias[n] + resid[(long)m * 512 + n];
        }
      }
}

// ------------------------------ softmax-diff-L1, one wave per row ------------
__global__ void softmax_diff_kernel(const float* __restrict__ S1, const float* __restrict__ S2,
                                    const float* __restrict__ lamlog, f16* __restrict__ attn,
                                    int zofs) {
  const int rid = blockIdx.x * 4 + (threadIdx.x >> 6);
  const int lane = threadIdx.x & 63;
  const int z = rid >> 9, i = rid & 511;
  const float lam = 1.f / (1.f + __expf(-lamlog[(z + zofs) & 7]));
  const long base = (long)z * 262144 + (long)i * 512;
  const int c0 = lane * 4, c1 = 256 + lane * 4;
  float4 xa = *(const float4*)(S1 + base + c0);
  float4 xb = *(const float4*)(S1 + base + c1);
  float4 ya = *(const float4*)(S2 + base + c0);
  float4 yb = *(const float4*)(S2 + base + c1);
  float s1v[8] = {xa.x, xa.y, xa.z, xa.w, xb.x, xb.y, xb.z, xb.w};
  float s2v[8] = {ya.x, ya.y, ya.z, ya.w, yb.x, yb.y, yb.z, yb.w};
  int cols[8];
#pragma unroll
  for (int k = 0; k < 8; k++) cols[k] = (k < 4) ? (c0 + k) : (c1 + k - 4);
  float m1 = -3.0e38f, m2 = -3.0e38f;
#pragma unroll
  for (int k = 0; k < 8; k++)
    if (cols[k] <= i) { m1 = fmaxf(m1, s1v[k]); m2 = fmaxf(m2, s2v[k]); }
  m1 = wave_red_max64(m1);
  m2 = wave_red_max64(m2);
  float z1 = 0.f, z2 = 0.f, e1[8], e2[8];
#pragma unroll
  for (int k = 0; k < 8; k++) {
    const bool valid = cols[k] <= i;
    e1[k] = valid ? __expf(s1v[k] - m1) : 0.f;
    e2[k] = valid ? __expf(s2v[k] - m2) : 0.f;
    z1 += e1[k]; z2 += e2[k];
  }
  z1 = wave_red_sum64(z1);
  z2 = wave_red_sum64(z2);
  const float r1 = 1.f / z1, r2 = lam / z2;
  float p[8], l1 = 0.f;
#pragma unroll
  for (int k = 0; k < 8; k++) { p[k] = e1[k] * r1 - e2[k] * r2; l1 += fabsf(p[k]); }
  l1 = wave_red_sum64(l1);
  const float rn = 1.f / fmaxf(l1, 1e-6f);
  f16x4 o0 = {(f16)(p[0] * rn), (f16)(p[1] * rn), (f16)(p[2] * rn), (f16)(p[3] * rn)};
  f16x4 o1 = {(f16)(p[4] * rn), (f16)(p[5] * rn), (f16)(p[6] * rn), (f16)(p[7] * rn)};
  *(f16x4*)(attn + base + c0) = o0;
  *(f16x4*)(attn + base + c1) = o1;
}

// ------------------------------ eta precompute (column-parallel part) --------
// ema recursion is per-column (1 fma/step chain); |x-ema| reduce is off-chain.
__launch_bounds__(64, 1) __global__
void eta_part_kernel(const float* __restrict__ x2, float* __restrict__ part) {
  const int b = blockIdx.x >> 3, w = blockIdx.x & 7;
  const int lane = threadIdx.x;
  const float* xb = x2 + (long)b * 262144 + w * 64 + lane;
  float ema = 0.f;
  float xA = xb[0], xB = xb[512];
  for (int t = 0; t < 512; t += 2) {
    {
      float d = fabsf(xA - ema);
      ema = fmaf(0.95f, ema, 0.05f * xA);
      const long tn = (t + 2 < 512) ? t + 2 : 510;
      xA = xb[tn * 512];
      d = wave_red_sum64(d);
      if (lane == 0) part[((long)b * 512 + t) * 8 + w] = d;
    }
    {
      float d = fabsf(xB - ema);
      ema = fmaf(0.95f, ema, 0.05f * xB);
      const long tn = (t + 3 < 512) ? t + 3 : 511;
      xB = xb[tn * 512];
      d = wave_red_sum64(d);
      if (lane == 0) part[((long)b * 512 + t + 1) * 8 + w] = d;
    }
  }
}

// serial lrm scan (trivial): one thread per batch
__global__ void eta_scan_kernel(const float* __restrict__ part, const float* __restrict__ loglr,
                                float* __restrict__ eta) {
  if (threadIdx.x != 0) return;
  const int b = blockIdx.x;
  float ilr = expf(loglr[0]);
  ilr = fminf(fmaxf(ilr, 1e-5f), 1.f);
  float lrm = 1.f;
  const float* pb = part + (long)b * 4096;
#pragma unroll 4
  for (int t = 0; t < 512; t++) {
    float4 p0 = *(const float4*)(pb + t * 8);
    float4 p1 = *(const float4*)(pb + t * 8 + 4);
    float nov = ((p0.x + p0.y) + (p0.z + p0.w)) + ((p1.x + p1.y) + (p1.z + p1.w));
    nov *= (1.f / 512.f);
    const float ls = fminf(fmaxf(fmaf(3.f, nov, 1.f), 0.5f), 3.f);
    lrm = fmaf(0.95f, lrm, 0.05f * ls);
    eta[b * 512 + t] = ilr * lrm;
  }
}

// ------------------------------ TTT fast path --------------------------------
// 512 blocks x 64 threads (1 wave = 2 rows x 32 lanes, 16 cols/lane).
// No LDS, no barriers; x/xrow/eta double-buffered global->reg prefetch;
// allreduce via DPP + one ds_swizzle; norm partials written per-16-lane-group.
#define TTT_PREF(XQ, XROW, ETA, T)                                            \
  {                                                                           \
    const long tn_ = ((T) < 511 ? (long)(T) : 511L);                          \
    const float* pr_ = xc + tn_ * 512;                                        \
    XQ[0] = *(const float4*)(pr_);                                            \
    XQ[1] = *(const float4*)(pr_ + 4);                                        \
    XQ[2] = *(const float4*)(pr_ + 8);                                        \
    XQ[3] = *(const float4*)(pr_ + 12);                                       \
    XROW = xb[tn_ * 512 + row];                                               \
    ETA = er[tn_];                                                            \
  }

#define TTT_STEP(XQ, XROW, ETA, T)                                            \
  {                                                                           \
    float a0 = 0.f, a1 = 0.f, a2 = 0.f, a3 = 0.f;                             \
    a0 = fmaf(fw[0], XQ[0].x, a0);  a1 = fmaf(fw[1], XQ[0].y, a1);            \
    a2 = fmaf(fw[2], XQ[0].z, a2);  a3 = fmaf(fw[3], XQ[0].w, a3);            \
    a0 = fmaf(fw[4], XQ[1].x, a0);  a1 = fmaf(fw[5], XQ[1].y, a1);            \
    a2 = fmaf(fw[6], XQ[1].z, a2);  a3 = fmaf(fw[7], XQ[1].w, a3);            \
    a0 = fmaf(fw[8], XQ[2].x, a0);  a1 = fmaf(fw[9], XQ[2].y, a1);            \
    a2 = fmaf(fw[10], XQ[2].z, a2); a3 = fmaf(fw[11], XQ[2].w, a3);           \
    a0 = fmaf(fw[12], XQ[3].x, a0); a1 = fmaf(fw[13], XQ[3].y, a1);           \
    a2 = fmaf(fw[14], XQ[3].z, a2); a3 = fmaf(fw[15], XQ[3].w, a3);           \
    float p_ = (a0 + a1) + (a2 + a3);                                         \
    p_ = allred32(p_);                                                        \
    const float y_ = p_ + biasr;                                              \
    if ((lane & 31) == 0) ys[((long)b * 512 + (T)) * 512 + row] = y_;         \
    const float c1_ = (y_ - (XROW)) * (0.1f / 512.f);                         \
    const float e_ = (ETA);                                                   \
    const float xv_[16] = {XQ[0].x, XQ[0].y, XQ[0].z, XQ[0].w,                \
                           XQ[1].x, XQ[1].y, XQ[1].z, XQ[1].w,                \
                           XQ[2].x, XQ[2].y, XQ[2].z, XQ[2].w,                \
                           XQ[3].x, XQ[3].y, XQ[3].z, XQ[3].w};               \
    float n0 = 0.f, n1 = 0.f, n2 = 0.f, n3 = 0.f;                             \
    _Pragma("unroll")                                                         \
    for (int i_ = 0; i_ < 4; i_++) {                                          \
      mom[4*i_+0] = fmaf(0.9f, mom[4*i_+0], c1_ * xv_[4*i_+0]);               \
      fw[4*i_+0] = fmaf(-e_, mom[4*i_+0], fw[4*i_+0]);                        \
      n0 = fmaf(fw[4*i_+0], fw[4*i_+0], n0);                                  \
      mom[4*i_+1] = fmaf(0.9f, mom[4*i_+1], c1_ * xv_[4*i_+1]);               \
      fw[4*i_+1] = fmaf(-e_, mom[4*i_+1], fw[4*i_+1]);                        \
      n1 = fmaf(fw[4*i_+1], fw[4*i_+1], n1);                                  \
      mom[4*i_+2] = fmaf(0.9f, mom[4*i_+2], c1_ * xv_[4*i_+2]);               \
      fw[4*i_+2] = fmaf(-e_, mom[4*i_+2], fw[4*i_+2]);                        \
      n2 = fmaf(fw[4*i_+2], fw[4*i_+2], n2);                                  \
      mom[4*i_+3] = fmaf(0.9f, mom[4*i_+3], c1_ * xv_[4*i_+3]);               \
      fw[4*i_+3] = fmaf(-e_, mom[4*i_+3], fw[4*i_+3]);                        \
      n3 = fmaf(fw[4*i_+3], fw[4*i_+3], n3);                                  \
    }                                                                         \
    float nsq_ = (n0 + n1) + (n2 + n3);                                       \
    nsq_ = red16g(nsq_);                                                      \
    if ((lane & 15) == 0)                                                     \
      normpart[(((long)(T)) * 512 + blk) * 4 + (lane >> 4)] = nsq_;           \
  }

__launch_bounds__(64, 1) __global__
void ttt_fast_kernel(const float* __restrict__ x2, const float* __restrict__ base_w,
                     const float* __restrict__ tbias, const float* __restrict__ eta,
                     float* __restrict__ ys, float* __restrict__ normpart) {
  const int blk = blockIdx.x;
  const int b = blk >> 8;
  const int lane = threadIdx.x;
  const int c = lane & 31;
  const int row = ((blk & 255) << 1) + (lane >> 5);
  const float* xb = x2 + (long)b * 262144;
  const float* xc = xb + c * 16;
  const float* er = eta + b * 512;

  float fw[16], mom[16];
  {
    const float* bp = base_w + (long)row * 512 + c * 16;
#pragma unroll
    for (int i = 0; i < 4; i++) {
      float4 t4 = *(const float4*)(bp + i * 4);
      fw[i * 4 + 0] = t4.x; fw[i * 4 + 1] = t4.y; fw[i * 4 + 2] = t4.z; fw[i * 4 + 3] = t4.w;
    }
  }
#pragma unroll
  for (int i = 0; i < 16; i++) mom[i] = 0.f;
  const float biasr = tbias[row];

  float4 XA[4], XB[4];
  float xrA, xrB, etA, etB;
  TTT_PREF(XA, xrA, etA, 0);
  TTT_PREF(XB, xrB, etB, 1);
  for (int t = 0; t < 512; t += 2) {
    TTT_STEP(XA, xrA, etA, t);
    TTT_PREF(XA, xrA, etA, t + 2);
    TTT_STEP(XB, xrB, etB, t + 1);
    TTT_PREF(XB, xrB, etB, t + 3);
  }
}

// ------------------------------ verify: norm ever > 32? ----------------------
__global__ void verify_kernel(const float* __restrict__ normpart, int* __restrict__ flag) {
  const int t = blockIdx.x;        // 512 blocks, one per step
  const int tid = threadIdx.x;     // 512 threads, one per ttt block
  const int wave = tid >> 6, lane = tid & 63;
  float4 v = *(const float4*)(normpart + (((long)t * 512) + tid) * 4);
  float s = (v.x + v.y) + (v.z + v.w);
  s = wave_red_sum64(s);
  __shared__ float part[8];
  if (lane == 0) part[wave] = s;
  __syncthreads();
  if (tid == 0) {
    const float s0 = (part[0] + part[1]) + (part[2] + part[3]);  // batch 0
    const float s1 = (part[4] + part[5]) + (part[6] + part[7]);  // batch 1
    if (s0 > 1020.f || s1 > 1020.f) atomicOr(flag, 1);  // margin under 32^2
  }
}

// ------------------------------ TTT fallback (exact, with clip) --------------
__launch_bounds__(1024, 1) __global__
void ttt_fallback_kernel(const int* __restrict__ flag, const float* __restrict__ x2,
                         const float* __restrict__ base_w, const float* __restrict__ tbias,
                         const float* __restrict__ eta, float* __restrict__ ys,
                         float* __restrict__ fwg, float* __restrict__ momg) {
  if (flag[0] == 0) return;
  const int b = blockIdx.x;
  const int tid = threadIdx.x;
  const int wave = tid >> 6, lane = tid & 63;
  float* fw = fwg + (long)b * 262144;
  float* mm = momg + (long)b * 262144;
  for (int e = tid; e < 262144; e += 1024) { fw[e] = base_w[e]; mm[e] = 0.f; }
  __shared__ float xs[512], errs[512], red[16];
  const float* xb = x2 + (long)b * 262144;
  for (int t = 0; t < 512; t++) {
    __syncthreads();
    if (tid < 512) xs[tid] = xb[t * 512 + tid];
    __syncthreads();
    if (tid < 512) {
      float acc = 0.f;
      for (int c = 0; c < 512; c++) acc = fmaf(fw[(long)tid * 512 + c], xs[c], acc);
      const float y = acc + tbias[tid];
      ys[((long)b * 512 + t) * 512 + tid] = y;
      errs[tid] = (y - xs[tid]) * (1.f / 512.f);
    }
    __syncthreads();
    const float eta_t = eta[b * 512 + t];
    float nsq = 0.f;
    for (int e = tid; e < 262144; e += 1024) {
      const int r = e >> 9, c = e & 511;
      const float m2 = fmaf(0.9f, mm[e], 0.1f * errs[r] * xs[c]);
      mm[e] = m2;
      const float f2 = fmaf(-eta_t, m2, fw[e]);
      fw[e] = f2;
      nsq = fmaf(f2, f2, nsq);
    }
    nsq = wave_red_sum64(nsq);
    if (lane == 0) red[wave] = nsq;
    __syncthreads();
    if (tid == 0) {
      float s = 0.f;
      for (int w = 0; w < 16; w++) s += red[w];
      red[0] = s;
    }
    __syncthreads();
    const float norm = fmaxf(sqrtf(red[0]), 1e-6f);
    const float sc = fminf(32.f / norm, 1.f);
    if (sc < 1.f)
      for (int e = tid; e < 262144; e += 1024) fw[e] *= sc;
  }
}

// ------------------------------ host launch ------------------------------
extern "C" void kernel_launch(void* const* d_in, const int* in_sizes, int n_in,
                              void* d_out, int out_size, void* d_ws, size_t ws_size,
                              hipStream_t stream) {
  (void)in_sizes; (void)n_in; (void)out_size;
  const float* x      = (const float*)d_in[0];
  const float* Wq     = (const float*)d_in[1];
  const float* Wk1    = (const float*)d_in[2];
  const float* Wk2    = (const float*)d_in[3];
  const float* Wv     = (const float*)d_in[4];
  const float* Wo     = (const float*)d_in[5];
  const float* lamlog = (const float*)d_in[6];
  const float* ln1g   = (const float*)d_in[7];
  const float* ln1b   = (const float*)d_in[8];
  const float* basew  = (const float*)d_in[9];
  const float* tttb   = (const float*)d_in[10];
  const float* loglr  = (const float*)d_in[11];
  const float* ln2g   = (const float*)d_in[12];
  const float* ln2b   = (const float*)d_in[13];
  const float* W1     = (const float*)d_in[14];
  const float* b1     = (const float*)d_in[15];
  const float* W2     = (const float*)d_in[16];
  const float* b2     = (const float*)d_in[17];
  const float* ln3g   = (const float*)d_in[18];
  const float* ln3b   = (const float*)d_in[19];
  float* out = (float*)d_out;

  char* ws = (char*)d_ws;
  size_t off = 0;
  auto alloc = [&](size_t bytes) {
    size_t o = off;
    off += (bytes + 255) & ~(size_t)255;
    return o;
  };
  f16* WqH   = (f16*)(ws + alloc(262144 * 2));
  f16* Wk1H  = (f16*)(ws + alloc(262144 * 2));
  f16* Wk2H  = (f16*)(ws + alloc(262144 * 2));
  f16* WvH   = (f16*)(ws + alloc(262144 * 2));
  f16* WoH   = (f16*)(ws + alloc(262144 * 2));
  f16* W1H   = (f16*)(ws + alloc(1048576 * 2));
  f16* W2H   = (f16*)(ws + alloc(1048576 * 2));
  f16* xlnH  = (f16*)(ws + alloc(524288 * 2));
  f16* qh    = (f16*)(ws + alloc(524288 * 2));
  f16* k1h   = (f16*)(ws + alloc(524288 * 2));
  f16* k2h   = (f16*)(ws + alloc(524288 * 2));
  f16* vTh   = (f16*)(ws + alloc(524288 * 2));
  f16* obtd  = (f16*)(ws + alloc(524288 * 2));
  f16* x3h   = (f16*)(ws + alloc(524288 * 2));
  f16* zh    = (f16*)(ws + alloc(2097152 * 2));
  float* h1  = (float*)(ws + alloc(524288 * 4));
  float* x2  = (float*)(ws + alloc(524288 * 4));
  float* ysb = (float*)(ws + alloc(524288 * 4));
  float* h2  = (float*)(ws + alloc(524288 * 4));
  float* eta = (float*)(ws + alloc(1024 * 4));
  float* npt = (float*)(ws + alloc((size_t)512 * 512 * 4 * 4));  // 4MB norm partials
  float* nvp = (float*)(ws + alloc(2 * 512 * 8 * 4));            // eta partials
  int* flag  = (int*)(ws + alloc(256));
  float* fwfb  = (float*)(ws + alloc(524288 * 4));
  float* momfb = (float*)(ws + alloc(524288 * 4));

  int hc = 16;
  while (hc > 1 && off + (size_t)hc * (262144ull * 4 * 2 + 262144ull * 2) > ws_size) hc >>= 1;
  float* S1  = (float*)(ws + alloc((size_t)hc * 262144 * 4));
  float* S2  = (float*)(ws + alloc((size_t)hc * 262144 * 4));
  f16* attnb = (f16*)(ws + alloc((size_t)hc * 262144 * 2));

  // ---- weight casts to fp16 ----
  cvt_f16_kernel<<<256, 256, 0, stream>>>(Wq, WqH, 262144);
  cvt_f16_kernel<<<256, 256, 0, stream>>>(Wk1, Wk1H, 262144);
  cvt_f16_kernel<<<256, 256, 0, stream>>>(Wk2, Wk2H, 262144);
  cvt_f16_kernel<<<256, 256, 0, stream>>>(Wv, WvH, 262144);
  cvt_f16_kernel<<<256, 256, 0, stream>>>(Wo, WoH, 262144);
  cvt_f16_kernel<<<1024, 256, 0, stream>>>(W1, W1H, 1048576);
  cvt_f16_kernel<<<1024, 256, 0, stream>>>(W2, W2H, 1048576);

  // ---- LN1 -> xln (fp16) ----
  ln_kernel<<<256, 256, 0, stream>>>(x, nullptr, ln1g, ln1b, nullptr, nullptr, xlnH);

  // ---- q/k1/k2 projections, v transposed ----
  gemm_bt<EPI_HEADS><<<dim3(4, 8, 1), 256, 0, stream>>>(xlnH, WqH, 512, 512, 0, 0, qh, nullptr, nullptr, 512, 1.f, 0);
  gemm_bt<EPI_HEADS><<<dim3(4, 8, 1), 256, 0, stream>>>(xlnH, Wk1H, 512, 512, 0, 0, k1h, nullptr, nullptr, 512, 1.f, 0);
  gemm_bt<EPI_HEADS><<<dim3(4, 8, 1), 256, 0, stream>>>(xlnH, Wk2H, 512, 512, 0, 0, k2h, nullptr, nullptr, 512, 1.f, 0);
  gemm_bt<EPI_VT><<<dim3(4, 8, 1), 256, 0, stream>>>(xlnH, WvH, 512, 512, 0, 0, vTh, nullptr, nullptr, 512, 1.f, 0);

  // ---- attention ----
  const int nc = 16 / hc;
  for (int c = 0; c < nc; c++) {
    const int cs = c * hc;
    gemm_bt<EPI_SCORES><<<dim3(4, 4, hc), 256, 0, stream>>>(
        qh + (long)cs * 32768, k1h + (long)cs * 32768, 64, 64, 32768, 32768, S1,
        nullptr, nullptr, 64, 0.125f, 0);
    gemm_bt<EPI_SCORES><<<dim3(4, 4, hc), 256, 0, stream>>>(
        qh + (long)cs * 32768, k2h + (long)cs * 32768, 64, 64, 32768, 32768, S2,
        nullptr, nullptr, 64, 0.125f, 0);
    softmax_diff_kernel<<<hc * 128, 256, 0, stream>>>(S1, S2, lamlog, attnb, cs);
    gemm_bt<EPI_PV><<<dim3(1, 4, hc), 256, 0, stream>>>(
        attnb, vTh + (long)cs * 32768, 512, 512, 262144, 32768, obtd,
        nullptr, nullptr, 512, 1.f, cs);
  }

  // ---- Wo projection + residual -> h1 ----
  gemm_bt<EPI_WO><<<dim3(4, 8, 1), 256, 0, stream>>>(obtd, WoH, 512, 512, 0, 0, h1, nullptr, x, 512, 1.f, 0);

  // ---- LN2 -> x2 (f32) ----
  ln_kernel<<<256, 256, 0, stream>>>(h1, nullptr, ln2g, ln2b, nullptr, x2, nullptr);

  // ---- TTT ----
  hipMemsetAsync(flag, 0, 4, stream);
  eta_part_kernel<<<16, 64, 0, stream>>>(x2, nvp);
  eta_scan_kernel<<<2, 64, 0, stream>>>(nvp, loglr, eta);
  ttt_fast_kernel<<<512, 64, 0, stream>>>(x2, basew, tttb, eta, ysb, npt);
  verify_kernel<<<512, 512, 0, stream>>>(npt, flag);
  ttt_fallback_kernel<<<2, 1024, 0, stream>>>(flag, x2, basew, tttb, eta, ysb, fwfb, momfb);

  // ---- h2 = h1 + ys ; LN3 -> x3 (fp16) ----
  ln_kernel<<<256, 256, 0, stream>>>(h1, ysb, ln3g, ln3b, h2, nullptr, x3h);

  // ---- FFN ----
  gemm_bt<EPI_GELU><<<dim3(16, 8, 1), 256, 0, stream>>>(x3h, W1H, 512, 512, 0, 0, zh, b1, nullptr, 512, 1.f, 0);
  gemm_bt<EPI_OUT><<<dim3(4, 8, 1), 256, 0, stream>>>(zh, W2H, 2048, 2048, 0, 0, out, b2, h2, 2048, 1.f, 0);
}

// Round 3
// 358.710 us; speedup vs baseline: 2.4967x; 2.0653x over previous
//
#include <hip/hip_runtime.h>
#include <hip/hip_fp16.h>

typedef _Float16 f16;
typedef f16 f16x4 __attribute__((ext_vector_type(4)));
typedef f16 f16x8 __attribute__((ext_vector_type(8)));
typedef float f32x4 __attribute__((ext_vector_type(4)));
typedef unsigned uint2v __attribute__((ext_vector_type(2)));

#define DEVI static __device__ __forceinline__

DEVI void gload_lds16(const void* g, void* l) {
  __builtin_amdgcn_global_load_lds(
      (const __attribute__((address_space(1))) unsigned int*)g,
      (__attribute__((address_space(3))) unsigned int*)l, 16, 0, 0);
}

DEVI float wave_red_sum64(float v) {
#pragma unroll
  for (int m = 1; m < 64; m <<= 1) v += __shfl_xor(v, m, 64);
  return v;
}
DEVI float wave_red_max64(float v) {
#pragma unroll
  for (int m = 1; m < 64; m <<= 1) v = fmaxf(v, __shfl_xor(v, m, 64));
  return v;
}

// ---- cross-lane adds: DPP for xor1..8, permlane-swap for xor16/32 (all VALU) ----
template <int CTRL>
DEVI float dpp_addf(float v) {
  int s = __builtin_amdgcn_update_dpp(0, __float_as_int(v), CTRL, 0xF, 0xF, true);
  return v + __int_as_float(s);
}
DEVI float xor16_add(float v) {
#if __has_builtin(__builtin_amdgcn_permlane16_swap)
  uint2v r = __builtin_amdgcn_permlane16_swap(__float_as_uint(v), __float_as_uint(v), false, false);
  return __uint_as_float(r.x) + __uint_as_float(r.y);
#else
  int s = __builtin_amdgcn_ds_swizzle(__float_as_int(v), 0x401F);
  return v + __int_as_float(s);
#endif
}
DEVI float xor32_add(float v) {
#if __has_builtin(__builtin_amdgcn_permlane32_swap)
  uint2v r = __builtin_amdgcn_permlane32_swap(__float_as_uint(v), __float_as_uint(v), false, false);
  return __uint_as_float(r.x) + __uint_as_float(r.y);
#else
  int s = __builtin_amdgcn_ds_bpermute(((threadIdx.x & 63) ^ 32) << 2, __float_as_int(v));
  return v + __int_as_float(s);
#endif
}
DEVI float allred64(float v) {
  v = dpp_addf<0xB1>(v);   // xor1
  v = dpp_addf<0x4E>(v);   // xor2
  v = dpp_addf<0x141>(v);  // xor4 (row_half_mirror, uniform bits0-1)
  v = dpp_addf<0x140>(v);  // xor8 (row_mirror, uniform bits0-2)
  v = xor16_add(v);
  return xor32_add(v);
}
DEVI float red16g(float v) {  // reduce within 16-lane groups
  v = dpp_addf<0xB1>(v);
  v = dpp_addf<0x4E>(v);
  v = dpp_addf<0x141>(v);
  v = dpp_addf<0x140>(v);
  return v;
}

// ------------------------------ fused f32 -> f16 cast of all 7 weights -------
__global__ void cvt_all_kernel(const float* __restrict__ s0, const float* __restrict__ s1,
                               const float* __restrict__ s2, const float* __restrict__ s3,
                               const float* __restrict__ s4, const float* __restrict__ s5,
                               const float* __restrict__ s6, f16* __restrict__ d) {
  const int blk = blockIdx.x;
  const float* s; long dofs; int local;
  if (blk < 256)       { s = s0; dofs = 0;       local = blk; }
  else if (blk < 512)  { s = s1; dofs = 262144;  local = blk - 256; }
  else if (blk < 768)  { s = s2; dofs = 524288;  local = blk - 512; }
  else if (blk < 1024) { s = s3; dofs = 786432;  local = blk - 768; }
  else if (blk < 1280) { s = s4; dofs = 1048576; local = blk - 1024; }
  else if (blk < 2304) { s = s5; dofs = 1310720; local = blk - 1280; }
  else                 { s = s6; dofs = 2359296; local = blk - 2304; }
  const long i = (long)local * 1024 + threadIdx.x * 4;
  float4 v = *(const float4*)(s + i);
  f16x4 o = {(f16)v.x, (f16)v.y, (f16)v.z, (f16)v.w};
  *(f16x4*)(d + dofs + i) = o;
}

// ------------------------------ LayerNorm D=512 ------------------------------
__global__ void ln_kernel(const float* __restrict__ in, const float* __restrict__ add,
                          const float* __restrict__ g, const float* __restrict__ b,
                          float* __restrict__ sumout, float* __restrict__ lnf,
                          f16* __restrict__ lnh) {
  const int row = blockIdx.x * 4 + (threadIdx.x >> 6);
  const int lane = threadIdx.x & 63;
  const long base = (long)row * 512;
  const int c0 = lane * 4, c1 = 256 + lane * 4;
  float4 a0 = *(const float4*)(in + base + c0);
  float4 a1 = *(const float4*)(in + base + c1);
  if (add) {
    float4 d0 = *(const float4*)(add + base + c0);
    float4 d1 = *(const float4*)(add + base + c1);
    a0.x += d0.x; a0.y += d0.y; a0.z += d0.z; a0.w += d0.w;
    a1.x += d1.x; a1.y += d1.y; a1.z += d1.z; a1.w += d1.w;
  }
  if (sumout) {
    *(float4*)(sumout + base + c0) = a0;
    *(float4*)(sumout + base + c1) = a1;
  }
  float v[8] = {a0.x, a0.y, a0.z, a0.w, a1.x, a1.y, a1.z, a1.w};
  float s = 0.f;
#pragma unroll
  for (int k = 0; k < 8; k++) s += v[k];
  s = wave_red_sum64(s);
  const float mean = s * (1.f / 512.f);
  float vs = 0.f;
#pragma unroll
  for (int k = 0; k < 8; k++) { float d = v[k] - mean; vs += d * d; }
  vs = wave_red_sum64(vs);
  const float rstd = rsqrtf(vs * (1.f / 512.f) + 1e-5f);
  float4 g0 = *(const float4*)(g + c0), g1 = *(const float4*)(g + c1);
  float4 p0 = *(const float4*)(b + c0), p1 = *(const float4*)(b + c1);
  const float gg[8] = {g0.x, g0.y, g0.z, g0.w, g1.x, g1.y, g1.z, g1.w};
  const float bv[8] = {p0.x, p0.y, p0.z, p0.w, p1.x, p1.y, p1.z, p1.w};
  float y[8];
#pragma unroll
  for (int k = 0; k < 8; k++) y[k] = (v[k] - mean) * rstd * gg[k] + bv[k];
  if (lnf) {
    float4 o0 = {y[0], y[1], y[2], y[3]}, o1 = {y[4], y[5], y[6], y[7]};
    *(float4*)(lnf + base + c0) = o0;
    *(float4*)(lnf + base + c1) = o1;
  }
  if (lnh) {
    f16x4 o0 = {(f16)y[0], (f16)y[1], (f16)y[2], (f16)y[3]};
    f16x4 o1 = {(f16)y[4], (f16)y[5], (f16)y[6], (f16)y[7]};
    *(f16x4*)(lnh + base + c0) = o0;
    *(f16x4*)(lnh + base + c1) = o1;
  }
}

// ------------------------------ generic fp16 MFMA GEMM, C = A(MxK) * W(NxK)^T
enum { EPI_QKV = 0, EPI_SCORES = 2, EPI_PV = 3, EPI_WO = 4, EPI_GELU = 5, EPI_OUT = 6 };

template <int EPI>
__launch_bounds__(256, 1) __global__
void gemm_bt(const f16* __restrict__ A, const f16* __restrict__ W, int lda, int ldw,
             long Az, long Wz, void* __restrict__ dst, const float* __restrict__ bias,
             const float* __restrict__ resid, int K, float scale, int zofs, int hcp) {
  if (EPI == EPI_SCORES && blockIdx.x > blockIdx.y) return;  // causal tile skip
  __shared__ f16 lA[128 * 64];
  __shared__ f16 lB[128 * 64];
  const int tid = threadIdx.x;
  const int wave = tid >> 6, lane = tid & 63;
  const int z = blockIdx.z;
  const f16* Ab;
  const f16* Wb;
  if (EPI == EPI_SCORES) {
    const int v_ = (z >= hcp) ? 1 : 0, head = z - v_ * hcp;
    Ab = A + (long)head * 32768 + (long)blockIdx.y * 128 * lda;
    Wb = W + (long)v_ * 524288 + (long)head * 32768 + (long)blockIdx.x * 128 * ldw;
  } else {
    Ab = A + (long)z * Az + (long)blockIdx.y * 128 * lda;
    Wb = W + (long)z * Wz + (long)blockIdx.x * 128 * ldw;
  }

  f32x4 acc[4][4];
#pragma unroll
  for (int a = 0; a < 4; a++)
#pragma unroll
    for (int q = 0; q < 4; q++) acc[a][q] = (f32x4){0.f, 0.f, 0.f, 0.f};

  int srow[4], scol[4];
#pragma unroll
  for (int i = 0; i < 4; i++) {
    int c = i * 256 + tid;
    int row = c >> 3;
    int colb = (c & 7) << 4;
    srow[i] = row;
    scol[i] = (colb ^ ((row & 7) << 4)) >> 1;
  }

  for (int k0 = 0; k0 < K; k0 += 64) {
    __syncthreads();
#pragma unroll
    for (int i = 0; i < 4; i++) {
      const int le = (i * 256 + wave * 64) * 8;
      gload_lds16(Ab + (long)srow[i] * lda + k0 + scol[i], lA + le);
      gload_lds16(Wb + (long)srow[i] * ldw + k0 + scol[i], lB + le);
    }
    __syncthreads();
    const int wm = (wave >> 1) * 64, wn = (wave & 1) * 64;
#pragma unroll
    for (int km = 0; km < 2; km++) {
      const int kb = km * 64 + ((lane >> 4) << 4);
      f16x8 af[4], bfv[4];
#pragma unroll
      for (int mf = 0; mf < 4; mf++) {
        int r = wm + mf * 16 + (lane & 15);
        af[mf] = *(const f16x8*)((const char*)lA + r * 128 + (kb ^ ((r & 7) << 4)));
      }
#pragma unroll
      for (int nf = 0; nf < 4; nf++) {
        int r = wn + nf * 16 + (lane & 15);
        bfv[nf] = *(const f16x8*)((const char*)lB + r * 128 + (kb ^ ((r & 7) << 4)));
      }
#pragma unroll
      for (int mf = 0; mf < 4; mf++)
#pragma unroll
        for (int nf = 0; nf < 4; nf++)
          acc[mf][nf] = __builtin_amdgcn_mfma_f32_16x16x32_f16(af[mf], bfv[nf], acc[mf][nf], 0, 0, 0);
    }
  }

  const int wm = (wave >> 1) * 64, wn = (wave & 1) * 64;
  const int rbase = blockIdx.y * 128 + wm + ((lane >> 4) << 2);
  const int cbase = blockIdx.x * 128 + wn + (lane & 15);
#pragma unroll
  for (int mf = 0; mf < 4; mf++)
#pragma unroll
    for (int nf = 0; nf < 4; nf++)
#pragma unroll
      for (int j = 0; j < 4; j++) {
        const int m = rbase + mf * 16 + j;
        const int n = cbase + nf * 16;
        const float v = acc[mf][nf][j];
        if (EPI == EPI_QKV) {
          // z<3: q/k1/k2 heads layout [B,H,T,64]; z==3: v transposed [B,H,64,T]
          f16* d = (f16*)dst + (long)z * 524288;
          if (z < 3)
            d[(long)((m >> 9) * 8 + (n >> 6)) * 32768 + (m & 511) * 64 + (n & 63)] = (f16)v;
          else
            d[(long)((m >> 9) * 8 + (n >> 6)) * 32768 + (n & 63) * 512 + (m & 511)] = (f16)v;
        } else if (EPI == EPI_SCORES) {
          ((float*)dst)[(long)z * 262144 + (long)m * 512 + n] = v * scale;
        } else if (EPI == EPI_PV) {
          if (n < 64) {
            const int hh = z + zofs;
            ((f16*)dst)[(long)((hh >> 3) * 512 + m) * 512 + (hh & 7) * 64 + n] = (f16)v;
          }
        } else if (EPI == EPI_WO) {
          ((float*)dst)[(long)m * 512 + n] = v + resid[(long)m * 512 + n];
        } else if (EPI == EPI_GELU) {
          const float u = v + bias[n];
          ((f16*)dst)[(long)m * 2048 + n] = (f16)(0.5f * u * (1.f + erff(u * 0.70710678118f)));
        } else {
          ((float*)dst)[(long)m * 512 + n] = v + bias[n] + resid[(long)m * 512 + n];
        }
      }
}

// ------------------------------ softmax-diff-L1, one wave per row ------------
__global__ void softmax_diff_kernel(const float* __restrict__ S1, const float* __restrict__ S2,
                                    const float* __restrict__ lamlog, f16* __restrict__ attn,
                                    int zofs) {
  const int rid = blockIdx.x * 4 + (threadIdx.x >> 6);
  const int lane = threadIdx.x & 63;
  const int z = rid >> 9, i = rid & 511;
  const float lam = 1.f / (1.f + __expf(-lamlog[(z + zofs) & 7]));
  const long base = (long)z * 262144 + (long)i * 512;
  const int c0 = lane * 4, c1 = 256 + lane * 4;
  float4 xa = *(const float4*)(S1 + base + c0);
  float4 xb = *(const float4*)(S1 + base + c1);
  float4 ya = *(const float4*)(S2 + base + c0);
  float4 yb = *(const float4*)(S2 + base + c1);
  float s1v[8] = {xa.x, xa.y, xa.z, xa.w, xb.x, xb.y, xb.z, xb.w};
  float s2v[8] = {ya.x, ya.y, ya.z, ya.w, yb.x, yb.y, yb.z, yb.w};
  int cols[8];
#pragma unroll
  for (int k = 0; k < 8; k++) cols[k] = (k < 4) ? (c0 + k) : (c1 + k - 4);
  float m1 = -3.0e38f, m2 = -3.0e38f;
#pragma unroll
  for (int k = 0; k < 8; k++)
    if (cols[k] <= i) { m1 = fmaxf(m1, s1v[k]); m2 = fmaxf(m2, s2v[k]); }
  m1 = wave_red_max64(m1);
  m2 = wave_red_max64(m2);
  float z1 = 0.f, z2 = 0.f, e1[8], e2[8];
#pragma unroll
  for (int k = 0; k < 8; k++) {
    const bool valid = cols[k] <= i;
    e1[k] = valid ? __expf(s1v[k] - m1) : 0.f;
    e2[k] = valid ? __expf(s2v[k] - m2) : 0.f;
    z1 += e1[k]; z2 += e2[k];
  }
  z1 = wave_red_sum64(z1);
  z2 = wave_red_sum64(z2);
  const float r1 = 1.f / z1, r2 = lam / z2;
  float p[8], l1 = 0.f;
#pragma unroll
  for (int k = 0; k < 8; k++) { p[k] = e1[k] * r1 - e2[k] * r2; l1 += fabsf(p[k]); }
  l1 = wave_red_sum64(l1);
  const float rn = 1.f / fmaxf(l1, 1e-6f);
  f16x4 o0 = {(f16)(p[0] * rn), (f16)(p[1] * rn), (f16)(p[2] * rn), (f16)(p[3] * rn)};
  f16x4 o1 = {(f16)(p[4] * rn), (f16)(p[5] * rn), (f16)(p[6] * rn), (f16)(p[7] * rn)};
  *(f16x4*)(attn + base + c0) = o0;
  *(f16x4*)(attn + base + c1) = o1;
}

// ------------------------------ eta precompute, 3 stages ---------------------
// stage 1: per-column |x - ema| streaming (no cross-lane, chains independent)
__launch_bounds__(64, 1) __global__
void eta_diff_kernel(const float* __restrict__ x2, float* __restrict__ diff) {
  const int blk = blockIdx.x;  // 16: b = blk>>3, col group = blk&7
  const int b = blk >> 3;
  const int col = (blk & 7) * 64 + threadIdx.x;
  const float* xp = x2 + (long)b * 262144 + col;
  float* dp = diff + (long)b * 262144 + col;
  float ema = 0.f;
  float x0 = xp[0], x1 = xp[512], x2r = xp[1024], x3 = xp[1536];
  for (int t = 0; t < 512; t += 4) {
    dp[(long)t * 512] = fabsf(x0 - ema);
    ema = fmaf(0.95f, ema, 0.05f * x0);
    dp[(long)(t + 1) * 512] = fabsf(x1 - ema);
    ema = fmaf(0.95f, ema, 0.05f * x1);
    dp[(long)(t + 2) * 512] = fabsf(x2r - ema);
    ema = fmaf(0.95f, ema, 0.05f * x2r);
    dp[(long)(t + 3) * 512] = fabsf(x3 - ema);
    ema = fmaf(0.95f, ema, 0.05f * x3);
    const long tb = (t + 4 < 512) ? (long)(t + 4) * 512 : 0;
    x0 = xp[tb]; x1 = xp[tb + 512]; x2r = xp[tb + 1024]; x3 = xp[tb + 1536];
  }
}

// stage 2: reduce each (b,t) row of diffs -> nov[b*512+t] (already /512)
__global__ void eta_nov_kernel(const float* __restrict__ diff, float* __restrict__ nov) {
  const int row = blockIdx.x * 4 + (threadIdx.x >> 6);  // row = b*512+t
  const int lane = threadIdx.x & 63;
  const float* dp = diff + (long)row * 512 + lane * 4;
  float4 a0 = *(const float4*)dp;
  float4 a1 = *(const float4*)(dp + 256);
  float s = ((a0.x + a0.y) + (a0.z + a0.w)) + ((a1.x + a1.y) + (a1.z + a1.w));
  s = wave_red_sum64(s);
  if (lane == 0) nov[row] = s * (1.f / 512.f);
}

// stage 3: serial lrm scan
__global__ void eta_scan_kernel(const float* __restrict__ nov, const float* __restrict__ loglr,
                                float* __restrict__ eta) {
  if (threadIdx.x != 0) return;
  const int b = blockIdx.x;
  float ilr = expf(loglr[0]);
  ilr = fminf(fmaxf(ilr, 1e-5f), 1.f);
  float lrm = 1.f;
  const float* pb = nov + (long)b * 512;
#pragma unroll 8
  for (int t = 0; t < 512; t++) {
    const float ls = fminf(fmaxf(fmaf(3.f, pb[t], 1.f), 0.5f), 3.f);
    lrm = fmaf(0.95f, lrm, 0.05f * ls);
    eta[b * 512 + t] = ilr * lrm;
  }
}

// ------------------------------ TTT fast path --------------------------------
// 1024 blocks x 64 threads: one row per 64-lane wave, 8 cols/lane.
// 4-deep global->reg prefetch; allreduce all-VALU (DPP + permlane swaps).
#define TPREF(X0, X1, XR, ET, T)                                              \
  {                                                                           \
    const long tn_ = ((T) < 511 ? (long)(T) : 511L);                          \
    const float* pr_ = xc + tn_ * 512;                                        \
    X0 = *(const float4*)(pr_);                                               \
    X1 = *(const float4*)(pr_ + 4);                                           \
    XR = xb[tn_ * 512 + row];                                                 \
    ET = er[tn_];                                                             \
  }

#define TSTEP(X0, X1, XR, ET, T)                                              \
  {                                                                           \
    float a0_ = fw[0] * X0.x, a1_ = fw[1] * X0.y;                             \
    float a2_ = fw[2] * X0.z, a3_ = fw[3] * X0.w;                             \
    a0_ = fmaf(fw[4], X1.x, a0_); a1_ = fmaf(fw[5], X1.y, a1_);               \
    a2_ = fmaf(fw[6], X1.z, a2_); a3_ = fmaf(fw[7], X1.w, a3_);               \
    float p_ = (a0_ + a1_) + (a2_ + a3_);                                     \
    p_ = allred64(p_);                                                        \
    const float y_ = p_ + biasr;                                              \
    if (lane == 0) ys[((long)b * 512 + (T)) * 512 + row] = y_;                \
    const float c1_ = (y_ - (XR)) * (0.1f / 512.f);                           \
    const float e_ = (ET);                                                    \
    const float xv_[8] = {X0.x, X0.y, X0.z, X0.w, X1.x, X1.y, X1.z, X1.w};    \
    float n0_ = 0.f, n1_ = 0.f, n2_ = 0.f, n3_ = 0.f;                         \
    _Pragma("unroll")                                                         \
    for (int i_ = 0; i_ < 2; i_++) {                                          \
      mom[4*i_+0] = fmaf(0.9f, mom[4*i_+0], c1_ * xv_[4*i_+0]);               \
      fw[4*i_+0] = fmaf(-e_, mom[4*i_+0], fw[4*i_+0]);                        \
      n0_ = fmaf(fw[4*i_+0], fw[4*i_+0], n0_);                                \
      mom[4*i_+1] = fmaf(0.9f, mom[4*i_+1], c1_ * xv_[4*i_+1]);               \
      fw[4*i_+1] = fmaf(-e_, mom[4*i_+1], fw[4*i_+1]);                        \
      n1_ = fmaf(fw[4*i_+1], fw[4*i_+1], n1_);                                \
      mom[4*i_+2] = fmaf(0.9f, mom[4*i_+2], c1_ * xv_[4*i_+2]);               \
      fw[4*i_+2] = fmaf(-e_, mom[4*i_+2], fw[4*i_+2]);                        \
      n2_ = fmaf(fw[4*i_+2], fw[4*i_+2], n2_);                                \
      mom[4*i_+3] = fmaf(0.9f, mom[4*i_+3], c1_ * xv_[4*i_+3]);               \
      fw[4*i_+3] = fmaf(-e_, mom[4*i_+3], fw[4*i_+3]);                        \
      n3_ = fmaf(fw[4*i_+3], fw[4*i_+3], n3_);                                \
    }                                                                         \
    float nsq_ = (n0_ + n1_) + (n2_ + n3_);                                   \
    nsq_ = red16g(nsq_);                                                      \
    if ((lane & 15) == 0)                                                     \
      normpart[(((long)(T)) * 1024 + blk) * 4 + (lane >> 4)] = nsq_;          \
  }

__launch_bounds__(64, 1) __global__
void ttt_fast_kernel(const float* __restrict__ x2, const float* __restrict__ base_w,
                     const float* __restrict__ tbias, const float* __restrict__ eta,
                     float* __restrict__ ys, float* __restrict__ normpart) {
  const int blk = blockIdx.x;   // 1024
  const int b = blk >> 9;
  const int row = blk & 511;
  const int lane = threadIdx.x;
  const float* xb = x2 + (long)b * 262144;
  const float* xc = xb + lane * 8;
  const float* er = eta + b * 512;

  float fw[8], mom[8];
  {
    const float* bp = base_w + (long)row * 512 + lane * 8;
    float4 f0 = *(const float4*)bp, f1 = *(const float4*)(bp + 4);
    fw[0] = f0.x; fw[1] = f0.y; fw[2] = f0.z; fw[3] = f0.w;
    fw[4] = f1.x; fw[5] = f1.y; fw[6] = f1.z; fw[7] = f1.w;
  }
#pragma unroll
  for (int i = 0; i < 8; i++) mom[i] = 0.f;
  const float biasr = tbias[row];

  float4 XA0, XA1, XB0, XB1, XC0, XC1, XD0, XD1;
  float xrA, xrB, xrC, xrD, etA, etB, etC, etD;
  TPREF(XA0, XA1, xrA, etA, 0);
  TPREF(XB0, XB1, xrB, etB, 1);
  TPREF(XC0, XC1, xrC, etC, 2);
  TPREF(XD0, XD1, xrD, etD, 3);
  for (int t = 0; t < 512; t += 4) {
    TSTEP(XA0, XA1, xrA, etA, t);
    TPREF(XA0, XA1, xrA, etA, t + 4);
    TSTEP(XB0, XB1, xrB, etB, t + 1);
    TPREF(XB0, XB1, xrB, etB, t + 5);
    TSTEP(XC0, XC1, xrC, etC, t + 2);
    TPREF(XC0, XC1, xrC, etC, t + 6);
    TSTEP(XD0, XD1, xrD, etD, t + 3);
    TPREF(XD0, XD1, xrD, etD, t + 7);
  }
}

// ------------------------------ verify: norm ever > 32? ----------------------
__global__ void verify_kernel(const float* __restrict__ normpart, int* __restrict__ flag) {
  const int t = blockIdx.x;        // 512 blocks, one per step
  const int tid = threadIdx.x;     // 1024 threads, one per ttt block
  const int wave = tid >> 6, lane = tid & 63;
  float4 v = *(const float4*)(normpart + (((long)t * 1024) + tid) * 4);
  float s = (v.x + v.y) + (v.z + v.w);
  s = wave_red_sum64(s);
  __shared__ float part[16];
  if (lane == 0) part[wave] = s;
  __syncthreads();
  if (tid == 0) {
    float s0 = 0.f, s1 = 0.f;
#pragma unroll
    for (int w = 0; w < 8; w++) { s0 += part[w]; s1 += part[8 + w]; }
    if (s0 > 1020.f || s1 > 1020.f) atomicOr(flag, 1);  // margin under 32^2=1024
  }
}

// ------------------------------ TTT fallback (exact, with clip) --------------
__launch_bounds__(1024, 1) __global__
void ttt_fallback_kernel(const int* __restrict__ flag, const float* __restrict__ x2,
                         const float* __restrict__ base_w, const float* __restrict__ tbias,
                         const float* __restrict__ eta, float* __restrict__ ys,
                         float* __restrict__ fwg, float* __restrict__ momg) {
  if (flag[0] == 0) return;
  const int b = blockIdx.x;
  const int tid = threadIdx.x;
  const int wave = tid >> 6, lane = tid & 63;
  float* fw = fwg + (long)b * 262144;
  float* mm = momg + (long)b * 262144;
  for (int e = tid; e < 262144; e += 1024) { fw[e] = base_w[e]; mm[e] = 0.f; }
  __shared__ float xs[512], errs[512], red[16];
  const float* xb = x2 + (long)b * 262144;
  for (int t = 0; t < 512; t++) {
    __syncthreads();
    if (tid < 512) xs[tid] = xb[t * 512 + tid];
    __syncthreads();
    if (tid < 512) {
      float acc = 0.f;
      for (int c = 0; c < 512; c++) acc = fmaf(fw[(long)tid * 512 + c], xs[c], acc);
      const float y = acc + tbias[tid];
      ys[((long)b * 512 + t) * 512 + tid] = y;
      errs[tid] = (y - xs[tid]) * (1.f / 512.f);
    }
    __syncthreads();
    const float eta_t = eta[b * 512 + t];
    float nsq = 0.f;
    for (int e = tid; e < 262144; e += 1024) {
      const int r = e >> 9, c = e & 511;
      const float m2 = fmaf(0.9f, mm[e], 0.1f * errs[r] * xs[c]);
      mm[e] = m2;
      const float f2 = fmaf(-eta_t, m2, fw[e]);
      fw[e] = f2;
      nsq = fmaf(f2, f2, nsq);
    }
    nsq = wave_red_sum64(nsq);
    if (lane == 0) red[wave] = nsq;
    __syncthreads();
    if (tid == 0) {
      float s = 0.f;
      for (int w = 0; w < 16; w++) s += red[w];
      red[0] = s;
    }
    __syncthreads();
    const float norm = fmaxf(sqrtf(red[0]), 1e-6f);
    const float sc = fminf(32.f / norm, 1.f);
    if (sc < 1.f)
      for (int e = tid; e < 262144; e += 1024) fw[e] *= sc;
  }
}

// ------------------------------ host launch ------------------------------
extern "C" void kernel_launch(void* const* d_in, const int* in_sizes, int n_in,
                              void* d_out, int out_size, void* d_ws, size_t ws_size,
                              hipStream_t stream) {
  (void)in_sizes; (void)n_in; (void)out_size;
  const float* x      = (const float*)d_in[0];
  const float* Wq     = (const float*)d_in[1];
  const float* Wk1    = (const float*)d_in[2];
  const float* Wk2    = (const float*)d_in[3];
  const float* Wv     = (const float*)d_in[4];
  const float* Wo     = (const float*)d_in[5];
  const float* lamlog = (const float*)d_in[6];
  const float* ln1g   = (const float*)d_in[7];
  const float* ln1b   = (const float*)d_in[8];
  const float* basew  = (const float*)d_in[9];
  const float* tttb   = (const float*)d_in[10];
  const float* loglr  = (const float*)d_in[11];
  const float* ln2g   = (const float*)d_in[12];
  const float* ln2b   = (const float*)d_in[13];
  const float* W1     = (const float*)d_in[14];
  const float* b1     = (const float*)d_in[15];
  const float* W2     = (const float*)d_in[16];
  const float* b2     = (const float*)d_in[17];
  const float* ln3g   = (const float*)d_in[18];
  const float* ln3b   = (const float*)d_in[19];
  float* out = (float*)d_out;

  char* ws = (char*)d_ws;
  size_t off = 0;
  auto alloc = [&](size_t bytes) {
    size_t o = off;
    off += (bytes + 255) & ~(size_t)255;
    return o;
  };
  // weights fp16, contiguous: Wq,Wk1,Wk2,Wv,Wo,W1,W2
  f16* WqH   = (f16*)(ws + alloc(262144 * 2));
  f16* Wk1H  = (f16*)(ws + alloc(262144 * 2));
  f16* Wk2H  = (f16*)(ws + alloc(262144 * 2));
  f16* WvH   = (f16*)(ws + alloc(262144 * 2));
  f16* WoH   = (f16*)(ws + alloc(262144 * 2));
  f16* W1H   = (f16*)(ws + alloc(1048576 * 2));
  f16* W2H   = (f16*)(ws + alloc(1048576 * 2));
  (void)Wk1H; (void)Wk2H; (void)WvH; (void)W1H;
  f16* xlnH  = (f16*)(ws + alloc(524288 * 2));
  // q,k1,k2,vT contiguous (QKV fused epilogue indexes by z)
  f16* qh    = (f16*)(ws + alloc(524288 * 2));
  f16* k1h   = (f16*)(ws + alloc(524288 * 2));
  f16* k2h   = (f16*)(ws + alloc(524288 * 2));
  f16* vTh   = (f16*)(ws + alloc(524288 * 2));
  (void)k2h;
  f16* obtd  = (f16*)(ws + alloc(524288 * 2));  // right after vTh (PV over-read pad)
  f16* x3h   = (f16*)(ws + alloc(524288 * 2));
  f16* zh    = (f16*)(ws + alloc(2097152 * 2));
  float* h1  = (float*)(ws + alloc(524288 * 4));
  float* x2  = (float*)(ws + alloc(524288 * 4));
  float* ysb = (float*)(ws + alloc(524288 * 4));
  float* h2  = (float*)(ws + alloc(524288 * 4));
  float* eta = (float*)(ws + alloc(1024 * 4));
  float* npt = (float*)(ws + alloc((size_t)512 * 1024 * 4 * 4));  // 8MB norm partials
  float* nvd = (float*)(ws + alloc(524288 * 4));                  // eta diffs
  float* nov = (float*)(ws + alloc(1024 * 4));
  int* flag  = (int*)(ws + alloc(256));
  float* fwfb  = (float*)(ws + alloc(524288 * 4));
  float* momfb = (float*)(ws + alloc(524288 * 4));

  int hc = 16;
  while (hc > 1 && off + (size_t)hc * (262144ull * 4 * 2 + 262144ull * 2) > ws_size) hc >>= 1;
  float* S1  = (float*)(ws + alloc((size_t)hc * 262144 * 4));  // S2 = S1 + hc*262144
  float* S2  = (float*)(ws + alloc((size_t)hc * 262144 * 4));
  f16* attnb = (f16*)(ws + alloc((size_t)hc * 262144 * 2));
  (void)S2;

  // ---- all weight casts in one launch ----
  cvt_all_kernel<<<3328, 256, 0, stream>>>(Wq, Wk1, Wk2, Wv, Wo, W1, W2, WqH);

  // ---- LN1 -> xln (fp16) ----
  ln_kernel<<<256, 256, 0, stream>>>(x, nullptr, ln1g, ln1b, nullptr, nullptr, xlnH);

  // ---- q/k1/k2/vT in one launch (z selects weight + epilogue) ----
  gemm_bt<EPI_QKV><<<dim3(4, 8, 4), 256, 0, stream>>>(
      xlnH, WqH, 512, 512, 0, 262144, qh, nullptr, nullptr, 512, 1.f, 0, 0);

  // ---- attention ----
  const int nc = 16 / hc;
  for (int c = 0; c < nc; c++) {
    const int cs = c * hc;
    gemm_bt<EPI_SCORES><<<dim3(4, 4, 2 * hc), 256, 0, stream>>>(
        qh + (long)cs * 32768, k1h + (long)cs * 32768, 64, 64, 0, 0, S1,
        nullptr, nullptr, 64, 0.125f, 0, hc);
    softmax_diff_kernel<<<hc * 128, 256, 0, stream>>>(S1, S2, lamlog, attnb, cs);
    gemm_bt<EPI_PV><<<dim3(1, 4, hc), 256, 0, stream>>>(
        attnb, vTh + (long)cs * 32768, 512, 512, 262144, 32768, obtd,
        nullptr, nullptr, 512, 1.f, cs, 0);
  }

  // ---- Wo projection + residual -> h1 ----
  gemm_bt<EPI_WO><<<dim3(4, 8, 1), 256, 0, stream>>>(obtd, WoH, 512, 512, 0, 0, h1, nullptr, x, 512, 1.f, 0, 0);

  // ---- LN2 -> x2 (f32) ----
  ln_kernel<<<256, 256, 0, stream>>>(h1, nullptr, ln2g, ln2b, nullptr, x2, nullptr);

  // ---- TTT ----
  hipMemsetAsync(flag, 0, 4, stream);
  eta_diff_kernel<<<16, 64, 0, stream>>>(x2, nvd);
  eta_nov_kernel<<<256, 256, 0, stream>>>(nvd, nov);
  eta_scan_kernel<<<2, 64, 0, stream>>>(nov, loglr, eta);
  ttt_fast_kernel<<<1024, 64, 0, stream>>>(x2, basew, tttb, eta, ysb, npt);
  verify_kernel<<<512, 1024, 0, stream>>>(npt, flag);
  ttt_fallback_kernel<<<2, 1024, 0, stream>>>(flag, x2, basew, tttb, eta, ysb, fwfb, momfb);

  // ---- h2 = h1 + ys ; LN3 -> x3 (fp16) ----
  ln_kernel<<<256, 256, 0, stream>>>(h1, ysb, ln3g, ln3b, h2, nullptr, x3h);

  // ---- FFN ----
  gemm_bt<EPI_GELU><<<dim3(16, 8, 1), 256, 0, stream>>>(x3h, W1H, 512, 512, 0, 0, zh, b1, nullptr, 512, 1.f, 0, 0);
  gemm_bt<EPI_OUT><<<dim3(4, 8, 1), 256, 0, stream>>>(zh, W2H, 2048, 2048, 0, 0, out, b2, h2, 2048, 1.f, 0, 0);
}

// Round 4
// 318.809 us; speedup vs baseline: 2.8092x; 1.1252x over previous
//
#include <hip/hip_runtime.h>
#include <hip/hip_fp16.h>

typedef _Float16 f16;
typedef f16 f16x4 __attribute__((ext_vector_type(4)));
typedef f16 f16x8 __attribute__((ext_vector_type(8)));
typedef float f32x4 __attribute__((ext_vector_type(4)));
typedef unsigned uint2v __attribute__((ext_vector_type(2)));

#define DEVI static __device__ __forceinline__

DEVI void gload_lds16(const void* g, void* l) {
  __builtin_amdgcn_global_load_lds(
      (const __attribute__((address_space(1))) unsigned int*)g,
      (__attribute__((address_space(3))) unsigned int*)l, 16, 0, 0);
}

DEVI float wave_red_sum64(float v) {
#pragma unroll
  for (int m = 1; m < 64; m <<= 1) v += __shfl_xor(v, m, 64);
  return v;
}
DEVI float wave_red_max64(float v) {
#pragma unroll
  for (int m = 1; m < 64; m <<= 1) v = fmaxf(v, __shfl_xor(v, m, 64));
  return v;
}

// ---- cross-lane adds: DPP for xor1..8, permlane-swap for xor16/32 (all VALU) ----
template <int CTRL>
DEVI float dpp_addf(float v) {
  int s = __builtin_amdgcn_update_dpp(0, __float_as_int(v), CTRL, 0xF, 0xF, true);
  return v + __int_as_float(s);
}
DEVI float xor16_add(float v) {
#if __has_builtin(__builtin_amdgcn_permlane16_swap)
  uint2v r = __builtin_amdgcn_permlane16_swap(__float_as_uint(v), __float_as_uint(v), false, false);
  return __uint_as_float(r.x) + __uint_as_float(r.y);
#else
  int s = __builtin_amdgcn_ds_swizzle(__float_as_int(v), 0x401F);
  return v + __int_as_float(s);
#endif
}
DEVI float xor32_add(float v) {
#if __has_builtin(__builtin_amdgcn_permlane32_swap)
  uint2v r = __builtin_amdgcn_permlane32_swap(__float_as_uint(v), __float_as_uint(v), false, false);
  return __uint_as_float(r.x) + __uint_as_float(r.y);
#else
  int s = __builtin_amdgcn_ds_bpermute(((threadIdx.x & 63) ^ 32) << 2, __float_as_int(v));
  return v + __int_as_float(s);
#endif
}
DEVI float allred64(float v) {
  v = dpp_addf<0xB1>(v);   // xor1
  v = dpp_addf<0x4E>(v);   // xor2
  v = dpp_addf<0x141>(v);  // xor4 (row_half_mirror, uniform bits0-1)
  v = dpp_addf<0x140>(v);  // xor8 (row_mirror, uniform bits0-2)
  v = xor16_add(v);
  return xor32_add(v);
}
DEVI float red16g(float v) {  // reduce within 16-lane groups
  v = dpp_addf<0xB1>(v);
  v = dpp_addf<0x4E>(v);
  v = dpp_addf<0x141>(v);
  v = dpp_addf<0x140>(v);
  return v;
}

// ------------------------------ fused f32 -> f16 cast of all 7 weights -------
__global__ void cvt_all_kernel(const float* __restrict__ s0, const float* __restrict__ s1,
                               const float* __restrict__ s2, const float* __restrict__ s3,
                               const float* __restrict__ s4, const float* __restrict__ s5,
                               const float* __restrict__ s6, f16* __restrict__ d) {
  const int blk = blockIdx.x;
  const float* s; long dofs; int local;
  if (blk < 256)       { s = s0; dofs = 0;       local = blk; }
  else if (blk < 512)  { s = s1; dofs = 262144;  local = blk - 256; }
  else if (blk < 768)  { s = s2; dofs = 524288;  local = blk - 512; }
  else if (blk < 1024) { s = s3; dofs = 786432;  local = blk - 768; }
  else if (blk < 1280) { s = s4; dofs = 1048576; local = blk - 1024; }
  else if (blk < 2304) { s = s5; dofs = 1310720; local = blk - 1280; }
  else                 { s = s6; dofs = 2359296; local = blk - 2304; }
  const long i = (long)local * 1024 + threadIdx.x * 4;
  float4 v = *(const float4*)(s + i);
  f16x4 o = {(f16)v.x, (f16)v.y, (f16)v.z, (f16)v.w};
  *(f16x4*)(d + dofs + i) = o;
}

// ------------------------------ LayerNorm D=512 ------------------------------
__global__ void ln_kernel(const float* __restrict__ in, const float* __restrict__ add,
                          const float* __restrict__ g, const float* __restrict__ b,
                          float* __restrict__ sumout, float* __restrict__ lnf,
                          f16* __restrict__ lnh) {
  const int row = blockIdx.x * 4 + (threadIdx.x >> 6);
  const int lane = threadIdx.x & 63;
  const long base = (long)row * 512;
  const int c0 = lane * 4, c1 = 256 + lane * 4;
  float4 a0 = *(const float4*)(in + base + c0);
  float4 a1 = *(const float4*)(in + base + c1);
  if (add) {
    float4 d0 = *(const float4*)(add + base + c0);
    float4 d1 = *(const float4*)(add + base + c1);
    a0.x += d0.x; a0.y += d0.y; a0.z += d0.z; a0.w += d0.w;
    a1.x += d1.x; a1.y += d1.y; a1.z += d1.z; a1.w += d1.w;
  }
  if (sumout) {
    *(float4*)(sumout + base + c0) = a0;
    *(float4*)(sumout + base + c1) = a1;
  }
  float v[8] = {a0.x, a0.y, a0.z, a0.w, a1.x, a1.y, a1.z, a1.w};
  float s = 0.f;
#pragma unroll
  for (int k = 0; k < 8; k++) s += v[k];
  s = wave_red_sum64(s);
  const float mean = s * (1.f / 512.f);
  float vs = 0.f;
#pragma unroll
  for (int k = 0; k < 8; k++) { float d = v[k] - mean; vs += d * d; }
  vs = wave_red_sum64(vs);
  const float rstd = rsqrtf(vs * (1.f / 512.f) + 1e-5f);
  float4 g0 = *(const float4*)(g + c0), g1 = *(const float4*)(g + c1);
  float4 p0 = *(const float4*)(b + c0), p1 = *(const float4*)(b + c1);
  const float gg[8] = {g0.x, g0.y, g0.z, g0.w, g1.x, g1.y, g1.z, g1.w};
  const float bv[8] = {p0.x, p0.y, p0.z, p0.w, p1.x, p1.y, p1.z, p1.w};
  float y[8];
#pragma unroll
  for (int k = 0; k < 8; k++) y[k] = (v[k] - mean) * rstd * gg[k] + bv[k];
  if (lnf) {
    float4 o0 = {y[0], y[1], y[2], y[3]}, o1 = {y[4], y[5], y[6], y[7]};
    *(float4*)(lnf + base + c0) = o0;
    *(float4*)(lnf + base + c1) = o1;
  }
  if (lnh) {
    f16x4 o0 = {(f16)y[0], (f16)y[1], (f16)y[2], (f16)y[3]};
    f16x4 o1 = {(f16)y[4], (f16)y[5], (f16)y[6], (f16)y[7]};
    *(f16x4*)(lnh + base + c0) = o0;
    *(f16x4*)(lnh + base + c1) = o1;
  }
}

// ------------------------------ generic fp16 MFMA GEMM, C = A(MxK) * W(NxK)^T
enum { EPI_QKV = 0, EPI_SCORES = 2, EPI_PV = 3, EPI_WO = 4, EPI_GELU = 5, EPI_OUT = 6 };

template <int EPI>
__launch_bounds__(256, 1) __global__
void gemm_bt(const f16* __restrict__ A, const f16* __restrict__ W, int lda, int ldw,
             long Az, long Wz, void* __restrict__ dst, const float* __restrict__ bias,
             const float* __restrict__ resid, int K, float scale, int zofs, int hcp) {
  if (EPI == EPI_SCORES && blockIdx.x > blockIdx.y) return;  // causal tile skip
  __shared__ f16 lA[128 * 64];
  __shared__ f16 lB[128 * 64];
  const int tid = threadIdx.x;
  const int wave = tid >> 6, lane = tid & 63;
  const int z = blockIdx.z;
  const f16* Ab;
  const f16* Wb;
  if (EPI == EPI_SCORES) {
    const int v_ = (z >= hcp) ? 1 : 0, head = z - v_ * hcp;
    Ab = A + (long)head * 32768 + (long)blockIdx.y * 128 * lda;
    Wb = W + (long)v_ * 524288 + (long)head * 32768 + (long)blockIdx.x * 128 * ldw;
  } else {
    Ab = A + (long)z * Az + (long)blockIdx.y * 128 * lda;
    Wb = W + (long)z * Wz + (long)blockIdx.x * 128 * ldw;
  }

  f32x4 acc[4][4];
#pragma unroll
  for (int a = 0; a < 4; a++)
#pragma unroll
    for (int q = 0; q < 4; q++) acc[a][q] = (f32x4){0.f, 0.f, 0.f, 0.f};

  int srow[4], scol[4];
#pragma unroll
  for (int i = 0; i < 4; i++) {
    int c = i * 256 + tid;
    int row = c >> 3;
    int colb = (c & 7) << 4;
    srow[i] = row;
    scol[i] = (colb ^ ((row & 7) << 4)) >> 1;
  }

  for (int k0 = 0; k0 < K; k0 += 64) {
    __syncthreads();
#pragma unroll
    for (int i = 0; i < 4; i++) {
      const int le = (i * 256 + wave * 64) * 8;
      gload_lds16(Ab + (long)srow[i] * lda + k0 + scol[i], lA + le);
      gload_lds16(Wb + (long)srow[i] * ldw + k0 + scol[i], lB + le);
    }
    __syncthreads();
    const int wm = (wave >> 1) * 64, wn = (wave & 1) * 64;
#pragma unroll
    for (int km = 0; km < 2; km++) {
      const int kb = km * 64 + ((lane >> 4) << 4);
      f16x8 af[4], bfv[4];
#pragma unroll
      for (int mf = 0; mf < 4; mf++) {
        int r = wm + mf * 16 + (lane & 15);
        af[mf] = *(const f16x8*)((const char*)lA + r * 128 + (kb ^ ((r & 7) << 4)));
      }
#pragma unroll
      for (int nf = 0; nf < 4; nf++) {
        int r = wn + nf * 16 + (lane & 15);
        bfv[nf] = *(const f16x8*)((const char*)lB + r * 128 + (kb ^ ((r & 7) << 4)));
      }
#pragma unroll
      for (int mf = 0; mf < 4; mf++)
#pragma unroll
        for (int nf = 0; nf < 4; nf++)
          acc[mf][nf] = __builtin_amdgcn_mfma_f32_16x16x32_f16(af[mf], bfv[nf], acc[mf][nf], 0, 0, 0);
    }
  }

  const int wm = (wave >> 1) * 64, wn = (wave & 1) * 64;
  const int rbase = blockIdx.y * 128 + wm + ((lane >> 4) << 2);
  const int cbase = blockIdx.x * 128 + wn + (lane & 15);
#pragma unroll
  for (int mf = 0; mf < 4; mf++)
#pragma unroll
    for (int nf = 0; nf < 4; nf++)
#pragma unroll
      for (int j = 0; j < 4; j++) {
        const int m = rbase + mf * 16 + j;
        const int n = cbase + nf * 16;
        const float v = acc[mf][nf][j];
        if (EPI == EPI_QKV) {
          // z<3: q/k1/k2 heads layout [B,H,T,64]; z==3: v transposed [B,H,64,T]
          f16* d = (f16*)dst + (long)z * 524288;
          if (z < 3)
            d[(long)((m >> 9) * 8 + (n >> 6)) * 32768 + (m & 511) * 64 + (n & 63)] = (f16)v;
          else
            d[(long)((m >> 9) * 8 + (n >> 6)) * 32768 + (n & 63) * 512 + (m & 511)] = (f16)v;
        } else if (EPI == EPI_SCORES) {
          ((float*)dst)[(long)z * 262144 + (long)m * 512 + n] = v * scale;
        } else if (EPI == EPI_PV) {
          if (n < 64) {
            const int hh = z + zofs;
            ((f16*)dst)[(long)((hh >> 3) * 512 + m) * 512 + (hh & 7) * 64 + n] = (f16)v;
          }
        } else if (EPI == EPI_WO) {
          ((float*)dst)[(long)m * 512 + n] = v + resid[(long)m * 512 + n];
        } else if (EPI == EPI_GELU) {
          const float u = v + bias[n];
          ((f16*)dst)[(long)m * 2048 + n] = (f16)(0.5f * u * (1.f + erff(u * 0.70710678118f)));
        } else {
          ((float*)dst)[(long)m * 512 + n] = v + bias[n] + resid[(long)m * 512 + n];
        }
      }
}

// ------------------------------ softmax-diff-L1, one wave per row ------------
__global__ void softmax_diff_kernel(const float* __restrict__ S1, const float* __restrict__ S2,
                                    const float* __restrict__ lamlog, f16* __restrict__ attn,
                                    int zofs) {
  const int rid = blockIdx.x * 4 + (threadIdx.x >> 6);
  const int lane = threadIdx.x & 63;
  const int z = rid >> 9, i = rid & 511;
  const float lam = 1.f / (1.f + __expf(-lamlog[(z + zofs) & 7]));
  const long base = (long)z * 262144 + (long)i * 512;
  const int c0 = lane * 4, c1 = 256 + lane * 4;
  float4 xa = *(const float4*)(S1 + base + c0);
  float4 xb = *(const float4*)(S1 + base + c1);
  float4 ya = *(const float4*)(S2 + base + c0);
  float4 yb = *(const float4*)(S2 + base + c1);
  float s1v[8] = {xa.x, xa.y, xa.z, xa.w, xb.x, xb.y, xb.z, xb.w};
  float s2v[8] = {ya.x, ya.y, ya.z, ya.w, yb.x, yb.y, yb.z, yb.w};
  int cols[8];
#pragma unroll
  for (int k = 0; k < 8; k++) cols[k] = (k < 4) ? (c0 + k) : (c1 + k - 4);
  float m1 = -3.0e38f, m2 = -3.0e38f;
#pragma unroll
  for (int k = 0; k < 8; k++)
    if (cols[k] <= i) { m1 = fmaxf(m1, s1v[k]); m2 = fmaxf(m2, s2v[k]); }
  m1 = wave_red_max64(m1);
  m2 = wave_red_max64(m2);
  float z1 = 0.f, z2 = 0.f, e1[8], e2[8];
#pragma unroll
  for (int k = 0; k < 8; k++) {
    const bool valid = cols[k] <= i;
    e1[k] = valid ? __expf(s1v[k] - m1) : 0.f;
    e2[k] = valid ? __expf(s2v[k] - m2) : 0.f;
    z1 += e1[k]; z2 += e2[k];
  }
  z1 = wave_red_sum64(z1);
  z2 = wave_red_sum64(z2);
  const float r1 = 1.f / z1, r2 = lam / z2;
  float p[8], l1 = 0.f;
#pragma unroll
  for (int k = 0; k < 8; k++) { p[k] = e1[k] * r1 - e2[k] * r2; l1 += fabsf(p[k]); }
  l1 = wave_red_sum64(l1);
  const float rn = 1.f / fmaxf(l1, 1e-6f);
  f16x4 o0 = {(f16)(p[0] * rn), (f16)(p[1] * rn), (f16)(p[2] * rn), (f16)(p[3] * rn)};
  f16x4 o1 = {(f16)(p[4] * rn), (f16)(p[5] * rn), (f16)(p[6] * rn), (f16)(p[7] * rn)};
  *(f16x4*)(attn + base + c0) = o0;
  *(f16x4*)(attn + base + c1) = o1;
}

// ------------------------------ eta precompute, 3 stages ---------------------
__launch_bounds__(64, 1) __global__
void eta_diff_kernel(const float* __restrict__ x2, float* __restrict__ diff) {
  const int blk = blockIdx.x;  // 16: b = blk>>3, col group = blk&7
  const int b = blk >> 3;
  const int col = (blk & 7) * 64 + threadIdx.x;
  const float* xp = x2 + (long)b * 262144 + col;
  float* dp = diff + (long)b * 262144 + col;
  float ema = 0.f;
  float x0 = xp[0], x1 = xp[512], x2r = xp[1024], x3 = xp[1536];
  for (int t = 0; t < 512; t += 4) {
    dp[(long)t * 512] = fabsf(x0 - ema);
    ema = fmaf(0.95f, ema, 0.05f * x0);
    dp[(long)(t + 1) * 512] = fabsf(x1 - ema);
    ema = fmaf(0.95f, ema, 0.05f * x1);
    dp[(long)(t + 2) * 512] = fabsf(x2r - ema);
    ema = fmaf(0.95f, ema, 0.05f * x2r);
    dp[(long)(t + 3) * 512] = fabsf(x3 - ema);
    ema = fmaf(0.95f, ema, 0.05f * x3);
    const long tb = (t + 4 < 512) ? (long)(t + 4) * 512 : 0;
    x0 = xp[tb]; x1 = xp[tb + 512]; x2r = xp[tb + 1024]; x3 = xp[tb + 1536];
  }
}

__global__ void eta_nov_kernel(const float* __restrict__ diff, float* __restrict__ nov) {
  const int row = blockIdx.x * 4 + (threadIdx.x >> 6);  // row = b*512+t
  const int lane = threadIdx.x & 63;
  const float* dp = diff + (long)row * 512 + lane * 4;
  float4 a0 = *(const float4*)dp;
  float4 a1 = *(const float4*)(dp + 256);
  float s = ((a0.x + a0.y) + (a0.z + a0.w)) + ((a1.x + a1.y) + (a1.z + a1.w));
  s = wave_red_sum64(s);
  if (lane == 0) nov[row] = s * (1.f / 512.f);
}

__global__ void eta_scan_kernel(const float* __restrict__ nov, const float* __restrict__ loglr,
                                float* __restrict__ eta) {
  if (threadIdx.x != 0) return;
  const int b = blockIdx.x;
  float ilr = expf(loglr[0]);
  ilr = fminf(fmaxf(ilr, 1e-5f), 1.f);
  float lrm = 1.f;
  const float* pb = nov + (long)b * 512;
#pragma unroll 8
  for (int t = 0; t < 512; t++) {
    const float ls = fminf(fmaxf(fmaf(3.f, pb[t], 1.f), 0.5f), 3.f);
    lrm = fmaf(0.95f, lrm, 0.05f * ls);
    eta[b * 512 + t] = ilr * lrm;
  }
}

// ------------------------------ TTT fast path --------------------------------
// 1024 blocks x 64 threads: one row per wave, 8 cols/lane.
// Inline-asm register prefetch (2 groups x 4 steps, lead = 8 steps) with
// counted s_waitcnt vmcnt(13) + sched_barrier(0) per group (T3/T4 + rule #18):
// the HIP scheduler otherwise sinks loads to their use (r3: VGPR=36 proved it).
#define ALD4(dst, p) asm volatile("global_load_dwordx4 %0, %1, off" : "=&v"(dst) : "v"(p) : "memory")
#define ALD1(dst, p) asm volatile("global_load_dword %0, %1, off" : "=&v"(dst) : "v"(p) : "memory")
#define VMWAIT13()                                                            \
  {                                                                           \
    asm volatile("s_waitcnt vmcnt(13)" ::: "memory");                         \
    __builtin_amdgcn_sched_barrier(0);                                        \
  }

// issue 13 loads for the next 4-step group; linear pointer advance (tail
// prefetch over-reads land in adjacent ws buffers and are never consumed)
#define TISSUE(X, XR, ET)                                                     \
  {                                                                           \
    ALD4(X[0], pxc);        ALD4(X[1], pxc + 4);                              \
    ALD4(X[2], pxc + 512);  ALD4(X[3], pxc + 516);                            \
    ALD4(X[4], pxc + 1024); ALD4(X[5], pxc + 1028);                           \
    ALD4(X[6], pxc + 1536); ALD4(X[7], pxc + 1540);                           \
    ALD1(XR[0], pxr);        ALD1(XR[1], pxr + 512);                          \
    ALD1(XR[2], pxr + 1024); ALD1(XR[3], pxr + 1536);                         \
    ALD4(ET, per);                                                            \
    pxc += 2048; pxr += 2048; per += 4;                                       \
  }

#define TSTEP(X0, X1, XRv, EV, T)                                             \
  {                                                                           \
    float a0_ = fw[0] * X0.x, a1_ = fw[1] * X0.y;                             \
    float a2_ = fw[2] * X0.z, a3_ = fw[3] * X0.w;                             \
    a0_ = fmaf(fw[4], X1.x, a0_); a1_ = fmaf(fw[5], X1.y, a1_);               \
    a2_ = fmaf(fw[6], X1.z, a2_); a3_ = fmaf(fw[7], X1.w, a3_);               \
    float p_ = (a0_ + a1_) + (a2_ + a3_);                                     \
    p_ = allred64(p_);                                                        \
    const float y_ = p_ + biasr;                                              \
    if (lane == 0) ys[ysofs + (long)(T) * 512] = y_;                          \
    const float c1_ = (y_ - (XRv)) * (0.1f / 512.f);                          \
    const float e_ = (EV);                                                    \
    const float xv_[8] = {X0.x, X0.y, X0.z, X0.w, X1.x, X1.y, X1.z, X1.w};    \
    float n0_ = 0.f, n1_ = 0.f, n2_ = 0.f, n3_ = 0.f;                         \
    _Pragma("unroll")                                                         \
    for (int i_ = 0; i_ < 2; i_++) {                                          \
      mom[4*i_+0] = fmaf(0.9f, mom[4*i_+0], c1_ * xv_[4*i_+0]);               \
      fw[4*i_+0] = fmaf(-e_, mom[4*i_+0], fw[4*i_+0]);                        \
      n0_ = fmaf(fw[4*i_+0], fw[4*i_+0], n0_);                                \
      mom[4*i_+1] = fmaf(0.9f, mom[4*i_+1], c1_ * xv_[4*i_+1]);               \
      fw[4*i_+1] = fmaf(-e_, mom[4*i_+1], fw[4*i_+1]);                        \
      n1_ = fmaf(fw[4*i_+1], fw[4*i_+1], n1_);                                \
      mom[4*i_+2] = fmaf(0.9f, mom[4*i_+2], c1_ * xv_[4*i_+2]);               \
      fw[4*i_+2] = fmaf(-e_, mom[4*i_+2], fw[4*i_+2]);                        \
      n2_ = fmaf(fw[4*i_+2], fw[4*i_+2], n2_);                                \
      mom[4*i_+3] = fmaf(0.9f, mom[4*i_+3], c1_ * xv_[4*i_+3]);               \
      fw[4*i_+3] = fmaf(-e_, mom[4*i_+3], fw[4*i_+3]);                        \
      n3_ = fmaf(fw[4*i_+3], fw[4*i_+3], n3_);                                \
    }                                                                         \
    float nsq_ = (n0_ + n1_) + (n2_ + n3_);                                   \
    nsq_ = red16g(nsq_);                                                      \
    if ((lane & 15) == 0)                                                     \
      normpart[(((long)(T)) * 1024 + blk) * 4 + (lane >> 4)] = nsq_;          \
  }

__launch_bounds__(64, 1) __global__
void ttt_fast_kernel(const float* __restrict__ x2, const float* __restrict__ base_w,
                     const float* __restrict__ tbias, const float* __restrict__ eta,
                     float* __restrict__ ys, float* __restrict__ normpart) {
  const int blk = blockIdx.x;   // 1024
  const int b = blk >> 9;
  const int row = blk & 511;
  const int lane = threadIdx.x;
  const float* xb = x2 + (long)b * 262144;
  const float* er = eta + b * 512;
  const long ysofs = (long)b * 262144 + row;

  float fw[8], mom[8];
  {
    const float* bp = base_w + (long)row * 512 + lane * 8;
    float4 f0 = *(const float4*)bp, f1 = *(const float4*)(bp + 4);
    fw[0] = f0.x; fw[1] = f0.y; fw[2] = f0.z; fw[3] = f0.w;
    fw[4] = f1.x; fw[5] = f1.y; fw[6] = f1.z; fw[7] = f1.w;
  }
#pragma unroll
  for (int i = 0; i < 8; i++) mom[i] = 0.f;
  const float biasr = tbias[row];

  const float* pxc = xb + lane * 8;
  const float* pxr = xb + row;
  const float* per = er;

  f32x4 XA[8], XB[8], EA, EB;
  float RA[4], RB[4];
  TISSUE(XA, RA, EA);
  TISSUE(XB, RB, EB);

#pragma unroll 1
  for (int T = 0; T < 512; T += 8) {
    VMWAIT13();
    TSTEP(XA[0], XA[1], RA[0], EA.x, T + 0);
    TSTEP(XA[2], XA[3], RA[1], EA.y, T + 1);
    TSTEP(XA[4], XA[5], RA[2], EA.z, T + 2);
    TSTEP(XA[6], XA[7], RA[3], EA.w, T + 3);
    TISSUE(XA, RA, EA);
    VMWAIT13();
    TSTEP(XB[0], XB[1], RB[0], EB.x, T + 4);
    TSTEP(XB[2], XB[3], RB[1], EB.y, T + 5);
    TSTEP(XB[4], XB[5], RB[2], EB.z, T + 6);
    TSTEP(XB[6], XB[7], RB[3], EB.w, T + 7);
    TISSUE(XB, RB, EB);
  }
  asm volatile("s_waitcnt vmcnt(0)" ::: "memory");
}

// ------------------------------ verify: norm ever > 32? ----------------------
__global__ void verify_kernel(const float* __restrict__ normpart, int* __restrict__ flag) {
  const int t = blockIdx.x;        // 512 blocks, one per step
  const int tid = threadIdx.x;     // 1024 threads, one per ttt block
  const int wave = tid >> 6, lane = tid & 63;
  float4 v = *(const float4*)(normpart + (((long)t * 1024) + tid) * 4);
  float s = (v.x + v.y) + (v.z + v.w);
  s = wave_red_sum64(s);
  __shared__ float part[16];
  if (lane == 0) part[wave] = s;
  __syncthreads();
  if (tid == 0) {
    float s0 = 0.f, s1 = 0.f;
#pragma unroll
    for (int w = 0; w < 8; w++) { s0 += part[w]; s1 += part[8 + w]; }
    if (s0 > 1020.f || s1 > 1020.f) atomicOr(flag, 1);  // margin under 32^2=1024
  }
}

// ------------------------------ TTT fallback (exact, with clip) --------------
__launch_bounds__(1024, 1) __global__
void ttt_fallback_kernel(const int* __restrict__ flag, const float* __restrict__ x2,
                         const float* __restrict__ base_w, const float* __restrict__ tbias,
                         const float* __restrict__ eta, float* __restrict__ ys,
                         float* __restrict__ fwg, float* __restrict__ momg) {
  if (flag[0] == 0) return;
  const int b = blockIdx.x;
  const int tid = threadIdx.x;
  const int wave = tid >> 6, lane = tid & 63;
  float* fw = fwg + (long)b * 262144;
  float* mm = momg + (long)b * 262144;
  for (int e = tid; e < 262144; e += 1024) { fw[e] = base_w[e]; mm[e] = 0.f; }
  __shared__ float xs[512], errs[512], red[16];
  const float* xb = x2 + (long)b * 262144;
  for (int t = 0; t < 512; t++) {
    __syncthreads();
    if (tid < 512) xs[tid] = xb[t * 512 + tid];
    __syncthreads();
    if (tid < 512) {
      float acc = 0.f;
      for (int c = 0; c < 512; c++) acc = fmaf(fw[(long)tid * 512 + c], xs[c], acc);
      const float y = acc + tbias[tid];
      ys[((long)b * 512 + t) * 512 + tid] = y;
      errs[tid] = (y - xs[tid]) * (1.f / 512.f);
    }
    __syncthreads();
    const float eta_t = eta[b * 512 + t];
    float nsq = 0.f;
    for (int e = tid; e < 262144; e += 1024) {
      const int r = e >> 9, c = e & 511;
      const float m2 = fmaf(0.9f, mm[e], 0.1f * errs[r] * xs[c]);
      mm[e] = m2;
      const float f2 = fmaf(-eta_t, m2, fw[e]);
      fw[e] = f2;
      nsq = fmaf(f2, f2, nsq);
    }
    nsq = wave_red_sum64(nsq);
    if (lane == 0) red[wave] = nsq;
    __syncthreads();
    if (tid == 0) {
      float s = 0.f;
      for (int w = 0; w < 16; w++) s += red[w];
      red[0] = s;
    }
    __syncthreads();
    const float norm = fmaxf(sqrtf(red[0]), 1e-6f);
    const float sc = fminf(32.f / norm, 1.f);
    if (sc < 1.f)
      for (int e = tid; e < 262144; e += 1024) fw[e] *= sc;
  }
}

// ------------------------------ host launch ------------------------------
extern "C" void kernel_launch(void* const* d_in, const int* in_sizes, int n_in,
                              void* d_out, int out_size, void* d_ws, size_t ws_size,
                              hipStream_t stream) {
  (void)in_sizes; (void)n_in; (void)out_size;
  const float* x      = (const float*)d_in[0];
  const float* Wq     = (const float*)d_in[1];
  const float* Wk1    = (const float*)d_in[2];
  const float* Wk2    = (const float*)d_in[3];
  const float* Wv     = (const float*)d_in[4];
  const float* Wo     = (const float*)d_in[5];
  const float* lamlog = (const float*)d_in[6];
  const float* ln1g   = (const float*)d_in[7];
  const float* ln1b   = (const float*)d_in[8];
  const float* basew  = (const float*)d_in[9];
  const float* tttb   = (const float*)d_in[10];
  const float* loglr  = (const float*)d_in[11];
  const float* ln2g   = (const float*)d_in[12];
  const float* ln2b   = (const float*)d_in[13];
  const float* W1     = (const float*)d_in[14];
  const float* b1     = (const float*)d_in[15];
  const float* W2     = (const float*)d_in[16];
  const float* b2     = (const float*)d_in[17];
  const float* ln3g   = (const float*)d_in[18];
  const float* ln3b   = (const float*)d_in[19];
  float* out = (float*)d_out;

  char* ws = (char*)d_ws;
  size_t off = 0;
  auto alloc = [&](size_t bytes) {
    size_t o = off;
    off += (bytes + 255) & ~(size_t)255;
    return o;
  };
  f16* WqH   = (f16*)(ws + alloc(262144 * 2));
  f16* Wk1H  = (f16*)(ws + alloc(262144 * 2));
  f16* Wk2H  = (f16*)(ws + alloc(262144 * 2));
  f16* WvH   = (f16*)(ws + alloc(262144 * 2));
  f16* WoH   = (f16*)(ws + alloc(262144 * 2));
  f16* W1H   = (f16*)(ws + alloc(1048576 * 2));
  f16* W2H   = (f16*)(ws + alloc(1048576 * 2));
  (void)Wk1H; (void)Wk2H; (void)WvH; (void)W1H;
  f16* xlnH  = (f16*)(ws + alloc(524288 * 2));
  f16* qh    = (f16*)(ws + alloc(524288 * 2));
  f16* k1h   = (f16*)(ws + alloc(524288 * 2));
  f16* k2h   = (f16*)(ws + alloc(524288 * 2));
  f16* vTh   = (f16*)(ws + alloc(524288 * 2));
  (void)k2h;
  f16* obtd  = (f16*)(ws + alloc(524288 * 2));
  f16* x3h   = (f16*)(ws + alloc(524288 * 2));
  f16* zh    = (f16*)(ws + alloc(2097152 * 2));
  float* h1  = (float*)(ws + alloc(524288 * 4));
  float* x2  = (float*)(ws + alloc(524288 * 4));
  float* ysb = (float*)(ws + alloc(524288 * 4));
  float* h2  = (float*)(ws + alloc(524288 * 4));
  float* eta = (float*)(ws + alloc(1024 * 4));
  float* npt = (float*)(ws + alloc((size_t)512 * 1024 * 4 * 4));  // 8MB norm partials
  float* nvd = (float*)(ws + alloc(524288 * 4));                  // eta diffs
  float* nov = (float*)(ws + alloc(1024 * 4));
  int* flag  = (int*)(ws + alloc(256));
  float* fwfb  = (float*)(ws + alloc(524288 * 4));
  float* momfb = (float*)(ws + alloc(524288 * 4));

  int hc = 16;
  while (hc > 1 && off + (size_t)hc * (262144ull * 4 * 2 + 262144ull * 2) > ws_size) hc >>= 1;
  float* S1  = (float*)(ws + alloc((size_t)hc * 262144 * 4));  // S2 = S1 + hc*262144
  float* S2  = (float*)(ws + alloc((size_t)hc * 262144 * 4));
  f16* attnb = (f16*)(ws + alloc((size_t)hc * 262144 * 2));
  (void)S2;

  // ---- all weight casts in one launch ----
  cvt_all_kernel<<<3328, 256, 0, stream>>>(Wq, Wk1, Wk2, Wv, Wo, W1, W2, WqH);

  // ---- LN1 -> xln (fp16) ----
  ln_kernel<<<256, 256, 0, stream>>>(x, nullptr, ln1g, ln1b, nullptr, nullptr, xlnH);

  // ---- q/k1/k2/vT in one launch (z selects weight + epilogue) ----
  gemm_bt<EPI_QKV><<<dim3(4, 8, 4), 256, 0, stream>>>(
      xlnH, WqH, 512, 512, 0, 262144, qh, nullptr, nullptr, 512, 1.f, 0, 0);

  // ---- attention ----
  const int nc = 16 / hc;
  for (int c = 0; c < nc; c++) {
    const int cs = c * hc;
    gemm_bt<EPI_SCORES><<<dim3(4, 4, 2 * hc), 256, 0, stream>>>(
        qh + (long)cs * 32768, k1h + (long)cs * 32768, 64, 64, 0, 0, S1,
        nullptr, nullptr, 64, 0.125f, 0, hc);
    softmax_diff_kernel<<<hc * 128, 256, 0, stream>>>(S1, S2, lamlog, attnb, cs);
    gemm_bt<EPI_PV><<<dim3(1, 4, hc), 256, 0, stream>>>(
        attnb, vTh + (long)cs * 32768, 512, 512, 262144, 32768, obtd,
        nullptr, nullptr, 512, 1.f, cs, 0);
  }

  // ---- Wo projection + residual -> h1 ----
  gemm_bt<EPI_WO><<<dim3(4, 8, 1), 256, 0, stream>>>(obtd, WoH, 512, 512, 0, 0, h1, nullptr, x, 512, 1.f, 0, 0);

  // ---- LN2 -> x2 (f32) ----
  ln_kernel<<<256, 256, 0, stream>>>(h1, nullptr, ln2g, ln2b, nullptr, x2, nullptr);

  // ---- TTT ----
  hipMemsetAsync(flag, 0, 4, stream);
  eta_diff_kernel<<<16, 64, 0, stream>>>(x2, nvd);
  eta_nov_kernel<<<256, 256, 0, stream>>>(nvd, nov);
  eta_scan_kernel<<<2, 64, 0, stream>>>(nov, loglr, eta);
  ttt_fast_kernel<<<1024, 64, 0, stream>>>(x2, basew, tttb, eta, ysb, npt);
  verify_kernel<<<512, 1024, 0, stream>>>(npt, flag);
  ttt_fallback_kernel<<<2, 1024, 0, stream>>>(flag, x2, basew, tttb, eta, ysb, fwfb, momfb);

  // ---- h2 = h1 + ys ; LN3 -> x3 (fp16) ----
  ln_kernel<<<256, 256, 0, stream>>>(h1, ysb, ln3g, ln3b, h2, nullptr, x3h);

  // ---- FFN ----
  gemm_bt<EPI_GELU><<<dim3(16, 8, 1), 256, 0, stream>>>(x3h, W1H, 512, 512, 0, 0, zh, b1, nullptr, 512, 1.f, 0, 0);
  gemm_bt<EPI_OUT><<<dim3(4, 8, 1), 256, 0, stream>>>(zh, W2H, 2048, 2048, 0, 0, out, b2, h2, 2048, 1.f, 0, 0);
}

// Round 5
// 312.996 us; speedup vs baseline: 2.8613x; 1.0186x over previous
//
#include <hip/hip_runtime.h>
#include <hip/hip_fp16.h>

typedef _Float16 f16;
typedef f16 f16x4 __attribute__((ext_vector_type(4)));
typedef f16 f16x8 __attribute__((ext_vector_type(8)));
typedef float f32x4 __attribute__((ext_vector_type(4)));
typedef unsigned uint2v __attribute__((ext_vector_type(2)));

#define DEVI static __device__ __forceinline__

DEVI void gload_lds16(const void* g, void* l) {
  __builtin_amdgcn_global_load_lds(
      (const __attribute__((address_space(1))) unsigned int*)g,
      (__attribute__((address_space(3))) unsigned int*)l, 16, 0, 0);
}

DEVI float wave_red_sum64(float v) {
#pragma unroll
  for (int m = 1; m < 64; m <<= 1) v += __shfl_xor(v, m, 64);
  return v;
}
DEVI float wave_red_max64(float v) {
#pragma unroll
  for (int m = 1; m < 64; m <<= 1) v = fmaxf(v, __shfl_xor(v, m, 64));
  return v;
}

// ---- cross-lane adds: DPP for xor1..8, permlane-swap for xor16/32 (all VALU) ----
template <int CTRL>
DEVI float dpp_addf(float v) {
  int s = __builtin_amdgcn_update_dpp(0, __float_as_int(v), CTRL, 0xF, 0xF, true);
  return v + __int_as_float(s);
}
DEVI float xor16_add(float v) {
#if __has_builtin(__builtin_amdgcn_permlane16_swap)
  uint2v r = __builtin_amdgcn_permlane16_swap(__float_as_uint(v), __float_as_uint(v), false, false);
  return __uint_as_float(r.x) + __uint_as_float(r.y);
#else
  int s = __builtin_amdgcn_ds_swizzle(__float_as_int(v), 0x401F);
  return v + __int_as_float(s);
#endif
}
DEVI float xor32_add(float v) {
#if __has_builtin(__builtin_amdgcn_permlane32_swap)
  uint2v r = __builtin_amdgcn_permlane32_swap(__float_as_uint(v), __float_as_uint(v), false, false);
  return __uint_as_float(r.x) + __uint_as_float(r.y);
#else
  int s = __builtin_amdgcn_ds_bpermute(((threadIdx.x & 63) ^ 32) << 2, __float_as_int(v));
  return v + __int_as_float(s);
#endif
}
DEVI float allred64(float v) {
  v = dpp_addf<0xB1>(v);   // xor1
  v = dpp_addf<0x4E>(v);   // xor2
  v = dpp_addf<0x141>(v);  // xor4 (row_half_mirror, uniform bits0-1)
  v = dpp_addf<0x140>(v);  // xor8 (row_mirror, uniform bits0-2)
  v = xor16_add(v);
  return xor32_add(v);
}
DEVI float red16g(float v) {  // reduce within 16-lane groups
  v = dpp_addf<0xB1>(v);
  v = dpp_addf<0x4E>(v);
  v = dpp_addf<0x141>(v);
  v = dpp_addf<0x140>(v);
  return v;
}

// ------------------------------ fused f32 -> f16 cast of all 7 weights -------
__global__ void cvt_all_kernel(const float* __restrict__ s0, const float* __restrict__ s1,
                               const float* __restrict__ s2, const float* __restrict__ s3,
                               const float* __restrict__ s4, const float* __restrict__ s5,
                               const float* __restrict__ s6, f16* __restrict__ d) {
  const int blk = blockIdx.x;
  const float* s; long dofs; int local;
  if (blk < 256)       { s = s0; dofs = 0;       local = blk; }
  else if (blk < 512)  { s = s1; dofs = 262144;  local = blk - 256; }
  else if (blk < 768)  { s = s2; dofs = 524288;  local = blk - 512; }
  else if (blk < 1024) { s = s3; dofs = 786432;  local = blk - 768; }
  else if (blk < 1280) { s = s4; dofs = 1048576; local = blk - 1024; }
  else if (blk < 2304) { s = s5; dofs = 1310720; local = blk - 1280; }
  else                 { s = s6; dofs = 2359296; local = blk - 2304; }
  const long i = (long)local * 1024 + threadIdx.x * 4;
  float4 v = *(const float4*)(s + i);
  f16x4 o = {(f16)v.x, (f16)v.y, (f16)v.z, (f16)v.w};
  *(f16x4*)(d + dofs + i) = o;
}

// ------------------------------ LayerNorm D=512 ------------------------------
__global__ void ln_kernel(const float* __restrict__ in, const float* __restrict__ add,
                          const float* __restrict__ g, const float* __restrict__ b,
                          float* __restrict__ sumout, float* __restrict__ lnf,
                          f16* __restrict__ lnh) {
  const int row = blockIdx.x * 4 + (threadIdx.x >> 6);
  const int lane = threadIdx.x & 63;
  const long base = (long)row * 512;
  const int c0 = lane * 4, c1 = 256 + lane * 4;
  float4 a0 = *(const float4*)(in + base + c0);
  float4 a1 = *(const float4*)(in + base + c1);
  if (add) {
    float4 d0 = *(const float4*)(add + base + c0);
    float4 d1 = *(const float4*)(add + base + c1);
    a0.x += d0.x; a0.y += d0.y; a0.z += d0.z; a0.w += d0.w;
    a1.x += d1.x; a1.y += d1.y; a1.z += d1.z; a1.w += d1.w;
  }
  if (sumout) {
    *(float4*)(sumout + base + c0) = a0;
    *(float4*)(sumout + base + c1) = a1;
  }
  float v[8] = {a0.x, a0.y, a0.z, a0.w, a1.x, a1.y, a1.z, a1.w};
  float s = 0.f;
#pragma unroll
  for (int k = 0; k < 8; k++) s += v[k];
  s = wave_red_sum64(s);
  const float mean = s * (1.f / 512.f);
  float vs = 0.f;
#pragma unroll
  for (int k = 0; k < 8; k++) { float d = v[k] - mean; vs += d * d; }
  vs = wave_red_sum64(vs);
  const float rstd = rsqrtf(vs * (1.f / 512.f) + 1e-5f);
  float4 g0 = *(const float4*)(g + c0), g1 = *(const float4*)(g + c1);
  float4 p0 = *(const float4*)(b + c0), p1 = *(const float4*)(b + c1);
  const float gg[8] = {g0.x, g0.y, g0.z, g0.w, g1.x, g1.y, g1.z, g1.w};
  const float bv[8] = {p0.x, p0.y, p0.z, p0.w, p1.x, p1.y, p1.z, p1.w};
  float y[8];
#pragma unroll
  for (int k = 0; k < 8; k++) y[k] = (v[k] - mean) * rstd * gg[k] + bv[k];
  if (lnf) {
    float4 o0 = {y[0], y[1], y[2], y[3]}, o1 = {y[4], y[5], y[6], y[7]};
    *(float4*)(lnf + base + c0) = o0;
    *(float4*)(lnf + base + c1) = o1;
  }
  if (lnh) {
    f16x4 o0 = {(f16)y[0], (f16)y[1], (f16)y[2], (f16)y[3]};
    f16x4 o1 = {(f16)y[4], (f16)y[5], (f16)y[6], (f16)y[7]};
    *(f16x4*)(lnh + base + c0) = o0;
    *(f16x4*)(lnh + base + c1) = o1;
  }
}

// ------------------------------ generic fp16 MFMA GEMM, C = A(MxK) * W(NxK)^T
enum { EPI_QKV = 0, EPI_SCORES = 2, EPI_PV = 3, EPI_WO = 4, EPI_GELU = 5, EPI_OUT = 6 };

template <int EPI>
__launch_bounds__(256, 1) __global__
void gemm_bt(const f16* __restrict__ A, const f16* __restrict__ W, int lda, int ldw,
             long Az, long Wz, void* __restrict__ dst, const float* __restrict__ bias,
             const float* __restrict__ resid, int K, float scale, int zofs, int hcp) {
  if (EPI == EPI_SCORES && blockIdx.x > blockIdx.y) return;  // causal tile skip
  __shared__ f16 lA[128 * 64];
  __shared__ f16 lB[128 * 64];
  const int tid = threadIdx.x;
  const int wave = tid >> 6, lane = tid & 63;
  const int z = blockIdx.z;
  const f16* Ab;
  const f16* Wb;
  if (EPI == EPI_SCORES) {
    const int v_ = (z >= hcp) ? 1 : 0, head = z - v_ * hcp;
    Ab = A + (long)head * 32768 + (long)blockIdx.y * 128 * lda;
    Wb = W + (long)v_ * 524288 + (long)head * 32768 + (long)blockIdx.x * 128 * ldw;
  } else {
    Ab = A + (long)z * Az + (long)blockIdx.y * 128 * lda;
    Wb = W + (long)z * Wz + (long)blockIdx.x * 128 * ldw;
  }

  f32x4 acc[4][4];
#pragma unroll
  for (int a = 0; a < 4; a++)
#pragma unroll
    for (int q = 0; q < 4; q++) acc[a][q] = (f32x4){0.f, 0.f, 0.f, 0.f};

  int srow[4], scol[4];
#pragma unroll
  for (int i = 0; i < 4; i++) {
    int c = i * 256 + tid;
    int row = c >> 3;
    int colb = (c & 7) << 4;
    srow[i] = row;
    scol[i] = (colb ^ ((row & 7) << 4)) >> 1;
  }

  for (int k0 = 0; k0 < K; k0 += 64) {
    __syncthreads();
#pragma unroll
    for (int i = 0; i < 4; i++) {
      const int le = (i * 256 + wave * 64) * 8;
      gload_lds16(Ab + (long)srow[i] * lda + k0 + scol[i], lA + le);
      gload_lds16(Wb + (long)srow[i] * ldw + k0 + scol[i], lB + le);
    }
    __syncthreads();
    const int wm = (wave >> 1) * 64, wn = (wave & 1) * 64;
#pragma unroll
    for (int km = 0; km < 2; km++) {
      const int kb = km * 64 + ((lane >> 4) << 4);
      f16x8 af[4], bfv[4];
#pragma unroll
      for (int mf = 0; mf < 4; mf++) {
        int r = wm + mf * 16 + (lane & 15);
        af[mf] = *(const f16x8*)((const char*)lA + r * 128 + (kb ^ ((r & 7) << 4)));
      }
#pragma unroll
      for (int nf = 0; nf < 4; nf++) {
        int r = wn + nf * 16 + (lane & 15);
        bfv[nf] = *(const f16x8*)((const char*)lB + r * 128 + (kb ^ ((r & 7) << 4)));
      }
#pragma unroll
      for (int mf = 0; mf < 4; mf++)
#pragma unroll
        for (int nf = 0; nf < 4; nf++)
          acc[mf][nf] = __builtin_amdgcn_mfma_f32_16x16x32_f16(af[mf], bfv[nf], acc[mf][nf], 0, 0, 0);
    }
  }

  const int wm = (wave >> 1) * 64, wn = (wave & 1) * 64;
  const int rbase = blockIdx.y * 128 + wm + ((lane >> 4) << 2);
  const int cbase = blockIdx.x * 128 + wn + (lane & 15);
#pragma unroll
  for (int mf = 0; mf < 4; mf++)
#pragma unroll
    for (int nf = 0; nf < 4; nf++)
#pragma unroll
      for (int j = 0; j < 4; j++) {
        const int m = rbase + mf * 16 + j;
        const int n = cbase + nf * 16;
        const float v = acc[mf][nf][j];
        if (EPI == EPI_QKV) {
          // z<3: q/k1/k2 heads layout [B,H,T,64]; z==3: v transposed [B,H,64,T]
          f16* d = (f16*)dst + (long)z * 524288;
          if (z < 3)
            d[(long)((m >> 9) * 8 + (n >> 6)) * 32768 + (m & 511) * 64 + (n & 63)] = (f16)v;
          else
            d[(long)((m >> 9) * 8 + (n >> 6)) * 32768 + (n & 63) * 512 + (m & 511)] = (f16)v;
        } else if (EPI == EPI_SCORES) {
          ((float*)dst)[(long)z * 262144 + (long)m * 512 + n] = v * scale;
        } else if (EPI == EPI_PV) {
          if (n < 64) {
            const int hh = z + zofs;
            ((f16*)dst)[(long)((hh >> 3) * 512 + m) * 512 + (hh & 7) * 64 + n] = (f16)v;
          }
        } else if (EPI == EPI_WO) {
          ((float*)dst)[(long)m * 512 + n] = v + resid[(long)m * 512 + n];
        } else if (EPI == EPI_GELU) {
          const float u = v + bias[n];
          ((f16*)dst)[(long)m * 2048 + n] = (f16)(0.5f * u * (1.f + erff(u * 0.70710678118f)));
        } else {
          ((float*)dst)[(long)m * 512 + n] = v + bias[n] + resid[(long)m * 512 + n];
        }
      }
}

// ------------------------------ softmax-diff-L1, one wave per row ------------
__global__ void softmax_diff_kernel(const float* __restrict__ S1, const float* __restrict__ S2,
                                    const float* __restrict__ lamlog, f16* __restrict__ attn,
                                    int zofs) {
  const int rid = blockIdx.x * 4 + (threadIdx.x >> 6);
  const int lane = threadIdx.x & 63;
  const int z = rid >> 9, i = rid & 511;
  const float lam = 1.f / (1.f + __expf(-lamlog[(z + zofs) & 7]));
  const long base = (long)z * 262144 + (long)i * 512;
  const int c0 = lane * 4, c1 = 256 + lane * 4;
  float4 xa = *(const float4*)(S1 + base + c0);
  float4 xb = *(const float4*)(S1 + base + c1);
  float4 ya = *(const float4*)(S2 + base + c0);
  float4 yb = *(const float4*)(S2 + base + c1);
  float s1v[8] = {xa.x, xa.y, xa.z, xa.w, xb.x, xb.y, xb.z, xb.w};
  float s2v[8] = {ya.x, ya.y, ya.z, ya.w, yb.x, yb.y, yb.z, yb.w};
  int cols[8];
#pragma unroll
  for (int k = 0; k < 8; k++) cols[k] = (k < 4) ? (c0 + k) : (c1 + k - 4);
  float m1 = -3.0e38f, m2 = -3.0e38f;
#pragma unroll
  for (int k = 0; k < 8; k++)
    if (cols[k] <= i) { m1 = fmaxf(m1, s1v[k]); m2 = fmaxf(m2, s2v[k]); }
  m1 = wave_red_max64(m1);
  m2 = wave_red_max64(m2);
  float z1 = 0.f, z2 = 0.f, e1[8], e2[8];
#pragma unroll
  for (int k = 0; k < 8; k++) {
    const bool valid = cols[k] <= i;
    e1[k] = valid ? __expf(s1v[k] - m1) : 0.f;
    e2[k] = valid ? __expf(s2v[k] - m2) : 0.f;
    z1 += e1[k]; z2 += e2[k];
  }
  z1 = wave_red_sum64(z1);
  z2 = wave_red_sum64(z2);
  const float r1 = 1.f / z1, r2 = lam / z2;
  float p[8], l1 = 0.f;
#pragma unroll
  for (int k = 0; k < 8; k++) { p[k] = e1[k] * r1 - e2[k] * r2; l1 += fabsf(p[k]); }
  l1 = wave_red_sum64(l1);
  const float rn = 1.f / fmaxf(l1, 1e-6f);
  f16x4 o0 = {(f16)(p[0] * rn), (f16)(p[1] * rn), (f16)(p[2] * rn), (f16)(p[3] * rn)};
  f16x4 o1 = {(f16)(p[4] * rn), (f16)(p[5] * rn), (f16)(p[6] * rn), (f16)(p[7] * rn)};
  *(f16x4*)(attn + base + c0) = o0;
  *(f16x4*)(attn + base + c1) = o1;
}

// ---- inline-asm load + counted-wait primitives (vmcnt counts LOADS AND STORES) ----
#define ALD4(dst, p) asm volatile("global_load_dwordx4 %0, %1, off" : "=&v"(dst) : "v"(p) : "memory")
#define ALD1(dst, p) asm volatile("global_load_dword %0, %1, off" : "=&v"(dst) : "v"(p) : "memory")
#define VMWAIT(N)                                                             \
  {                                                                           \
    asm volatile("s_waitcnt vmcnt(" #N ")" ::: "memory");                     \
    __builtin_amdgcn_sched_barrier(0);                                        \
  }

// ------------------------------ eta precompute, 3 stages ---------------------
// stage 1: per-column |x - ema| streaming; asm prefetch, 2 groups x 8 steps.
// Per group: 8 loads + 8 stores. Queue at loop wait: [cur 8ld][8st][next 8ld]
// -> vmcnt(16) drains exactly the current group's loads, leaves stores in flight.
#define EISSUE(X)                                                             \
  {                                                                           \
    ALD1(X[0], pe);        ALD1(X[1], pe + 512);                              \
    ALD1(X[2], pe + 1024); ALD1(X[3], pe + 1536);                             \
    ALD1(X[4], pe + 2048); ALD1(X[5], pe + 2560);                             \
    ALD1(X[6], pe + 3072); ALD1(X[7], pe + 3584);                             \
    pe += 4096;                                                               \
  }
#define ESTEP(V, T)                                                           \
  {                                                                           \
    dp[(long)(T) * 512] = fabsf((V) - ema);                                   \
    ema = fmaf(0.95f, ema, 0.05f * (V));                                      \
  }

__launch_bounds__(64, 1) __global__
void eta_diff_kernel(const float* __restrict__ x2, float* __restrict__ diff) {
  const int blk = blockIdx.x;  // 16: b = blk>>3, col group = blk&7
  const int b = blk >> 3;
  const int col = (blk & 7) * 64 + threadIdx.x;
  const float* pe = x2 + (long)b * 262144 + col;
  float* dp = diff + (long)b * 262144 + col;
  float ema = 0.f;
  float EA[8], EB[8];
  EISSUE(EA);
  EISSUE(EB);
  VMWAIT(8);
#pragma unroll 1
  for (int t = 0; t < 512; t += 16) {
    ESTEP(EA[0], t + 0); ESTEP(EA[1], t + 1); ESTEP(EA[2], t + 2); ESTEP(EA[3], t + 3);
    ESTEP(EA[4], t + 4); ESTEP(EA[5], t + 5); ESTEP(EA[6], t + 6); ESTEP(EA[7], t + 7);
    EISSUE(EA);
    VMWAIT(16);
    ESTEP(EB[0], t + 8);  ESTEP(EB[1], t + 9);  ESTEP(EB[2], t + 10); ESTEP(EB[3], t + 11);
    ESTEP(EB[4], t + 12); ESTEP(EB[5], t + 13); ESTEP(EB[6], t + 14); ESTEP(EB[7], t + 15);
    EISSUE(EB);
    VMWAIT(16);
  }
  asm volatile("s_waitcnt vmcnt(0)" ::: "memory");
}

__global__ void eta_nov_kernel(const float* __restrict__ diff, float* __restrict__ nov) {
  const int row = blockIdx.x * 4 + (threadIdx.x >> 6);  // row = b*512+t
  const int lane = threadIdx.x & 63;
  const float* dp = diff + (long)row * 512 + lane * 4;
  float4 a0 = *(const float4*)dp;
  float4 a1 = *(const float4*)(dp + 256);
  float s = ((a0.x + a0.y) + (a0.z + a0.w)) + ((a1.x + a1.y) + (a1.z + a1.w));
  s = wave_red_sum64(s);
  if (lane == 0) nov[row] = s * (1.f / 512.f);
}

__global__ void eta_scan_kernel(const float* __restrict__ nov, const float* __restrict__ loglr,
                                float* __restrict__ eta) {
  if (threadIdx.x != 0) return;
  const int b = blockIdx.x;
  float ilr = expf(loglr[0]);
  ilr = fminf(fmaxf(ilr, 1e-5f), 1.f);
  float lrm = 1.f;
  const float* pb = nov + (long)b * 512;
#pragma unroll 8
  for (int t = 0; t < 512; t++) {
    const float ls = fminf(fmaxf(fmaf(3.f, pb[t], 1.f), 0.5f), 3.f);
    lrm = fmaf(0.95f, lrm, 0.05f * ls);
    eta[b * 512 + t] = ilr * lrm;
  }
}

// ------------------------------ TTT fast path --------------------------------
// 1024 blocks x 64 threads: one row per wave, 8 cols/lane.
// Per 4-step group: 13 loads (TISSUE) + 8 stores (2/step inside TSTEP).
// Queue at loop wait: [cur 13ld][8st][next 13ld] = 34 -> vmcnt(21) drains
// exactly the current group's 13 loads and leaves the stores in flight
// (r4 bug: vmcnt(13) also drained the stores -> serialized on store retire).
#define TISSUE(X, XR, ET)                                                     \
  {                                                                           \
    ALD4(X[0], pxc);        ALD4(X[1], pxc + 4);                              \
    ALD4(X[2], pxc + 512);  ALD4(X[3], pxc + 516);                            \
    ALD4(X[4], pxc + 1024); ALD4(X[5], pxc + 1028);                           \
    ALD4(X[6], pxc + 1536); ALD4(X[7], pxc + 1540);                           \
    ALD1(XR[0], pxr);        ALD1(XR[1], pxr + 512);                          \
    ALD1(XR[2], pxr + 1024); ALD1(XR[3], pxr + 1536);                         \
    ALD4(ET, per);                                                            \
    pxc += 2048; pxr += 2048; per += 4;                                       \
  }

#define TSTEP(X0, X1, XRv, EV, T)                                             \
  {                                                                           \
    float a0_ = fw[0] * X0.x, a1_ = fw[1] * X0.y;                             \
    float a2_ = fw[2] * X0.z, a3_ = fw[3] * X0.w;                             \
    a0_ = fmaf(fw[4], X1.x, a0_); a1_ = fmaf(fw[5], X1.y, a1_);               \
    a2_ = fmaf(fw[6], X1.z, a2_); a3_ = fmaf(fw[7], X1.w, a3_);               \
    float p_ = (a0_ + a1_) + (a2_ + a3_);                                     \
    p_ = allred64(p_);                                                        \
    const float y_ = p_ + biasr;                                              \
    if (lane == 0) ys[ysofs + (long)(T) * 512] = y_;                          \
    const float c1_ = (y_ - (XRv)) * (0.1f / 512.f);                          \
    const float e_ = (EV);                                                    \
    const float xv_[8] = {X0.x, X0.y, X0.z, X0.w, X1.x, X1.y, X1.z, X1.w};    \
    float n0_ = 0.f, n1_ = 0.f, n2_ = 0.f, n3_ = 0.f;                         \
    _Pragma("unroll")                                                         \
    for (int i_ = 0; i_ < 2; i_++) {                                          \
      mom[4*i_+0] = fmaf(0.9f, mom[4*i_+0], c1_ * xv_[4*i_+0]);               \
      fw[4*i_+0] = fmaf(-e_, mom[4*i_+0], fw[4*i_+0]);                        \
      n0_ = fmaf(fw[4*i_+0], fw[4*i_+0], n0_);                                \
      mom[4*i_+1] = fmaf(0.9f, mom[4*i_+1], c1_ * xv_[4*i_+1]);               \
      fw[4*i_+1] = fmaf(-e_, mom[4*i_+1], fw[4*i_+1]);                        \
      n1_ = fmaf(fw[4*i_+1], fw[4*i_+1], n1_);                                \
      mom[4*i_+2] = fmaf(0.9f, mom[4*i_+2], c1_ * xv_[4*i_+2]);               \
      fw[4*i_+2] = fmaf(-e_, mom[4*i_+2], fw[4*i_+2]);                        \
      n2_ = fmaf(fw[4*i_+2], fw[4*i_+2], n2_);                                \
      mom[4*i_+3] = fmaf(0.9f, mom[4*i_+3], c1_ * xv_[4*i_+3]);               \
      fw[4*i_+3] = fmaf(-e_, mom[4*i_+3], fw[4*i_+3]);                        \
      n3_ = fmaf(fw[4*i_+3], fw[4*i_+3], n3_);                                \
    }                                                                         \
    float nsq_ = (n0_ + n1_) + (n2_ + n3_);                                   \
    nsq_ = red16g(nsq_);                                                      \
    if ((lane & 15) == 0)                                                     \
      normpart[(((long)(T)) * 1024 + blk) * 4 + (lane >> 4)] = nsq_;          \
  }

__launch_bounds__(64, 1) __global__
void ttt_fast_kernel(const float* __restrict__ x2, const float* __restrict__ base_w,
                     const float* __restrict__ tbias, const float* __restrict__ eta,
                     float* __restrict__ ys, float* __restrict__ normpart) {
  const int blk = blockIdx.x;   // 1024
  const int b = blk >> 9;
  const int row = blk & 511;
  const int lane = threadIdx.x;
  const float* xb = x2 + (long)b * 262144;
  const float* er = eta + b * 512;
  const long ysofs = (long)b * 262144 + row;

  float fw[8], mom[8];
  {
    const float* bp = base_w + (long)row * 512 + lane * 8;
    float4 f0 = *(const float4*)bp, f1 = *(const float4*)(bp + 4);
    fw[0] = f0.x; fw[1] = f0.y; fw[2] = f0.z; fw[3] = f0.w;
    fw[4] = f1.x; fw[5] = f1.y; fw[6] = f1.z; fw[7] = f1.w;
  }
#pragma unroll
  for (int i = 0; i < 8; i++) mom[i] = 0.f;
  const float biasr = tbias[row];

  const float* pxc = xb + lane * 8;
  const float* pxr = xb + row;
  const float* per = er;

  f32x4 XA[8], XB[8], EA, EB;
  float RA[4], RB[4];
  TISSUE(XA, RA, EA);
  TISSUE(XB, RB, EB);
  VMWAIT(13);  // queue = 26 loads; drain group A exactly

#pragma unroll 1
  for (int T = 0; T < 512; T += 8) {
    TSTEP(XA[0], XA[1], RA[0], EA.x, T + 0);
    TSTEP(XA[2], XA[3], RA[1], EA.y, T + 1);
    TSTEP(XA[4], XA[5], RA[2], EA.z, T + 2);
    TSTEP(XA[6], XA[7], RA[3], EA.w, T + 3);
    TISSUE(XA, RA, EA);
    VMWAIT(21);  // queue = [B 13ld][8st][A' 13ld]; drain B only
    TSTEP(XB[0], XB[1], RB[0], EB.x, T + 4);
    TSTEP(XB[2], XB[3], RB[1], EB.y, T + 5);
    TSTEP(XB[4], XB[5], RB[2], EB.z, T + 6);
    TSTEP(XB[6], XB[7], RB[3], EB.w, T + 7);
    TISSUE(XB, RB, EB);
    VMWAIT(21);  // drain [8st][A' 13ld]; A' ready for next iter
  }
  asm volatile("s_waitcnt vmcnt(0)" ::: "memory");
}

// ------------------------------ verify: norm ever > 32? ----------------------
__global__ void verify_kernel(const float* __restrict__ normpart, int* __restrict__ flag) {
  const int t = blockIdx.x;        // 512 blocks, one per step
  const int tid = threadIdx.x;     // 1024 threads, one per ttt block
  const int wave = tid >> 6, lane = tid & 63;
  float4 v = *(const float4*)(normpart + (((long)t * 1024) + tid) * 4);
  float s = (v.x + v.y) + (v.z + v.w);
  s = wave_red_sum64(s);
  __shared__ float part[16];
  if (lane == 0) part[wave] = s;
  __syncthreads();
  if (tid == 0) {
    float s0 = 0.f, s1 = 0.f;
#pragma unroll
    for (int w = 0; w < 8; w++) { s0 += part[w]; s1 += part[8 + w]; }
    if (s0 > 1020.f || s1 > 1020.f) atomicOr(flag, 1);  // margin under 32^2=1024
  }
}

// ------------------------------ TTT fallback (exact, with clip) --------------
__launch_bounds__(1024, 1) __global__
void ttt_fallback_kernel(const int* __restrict__ flag, const float* __restrict__ x2,
                         const float* __restrict__ base_w, const float* __restrict__ tbias,
                         const float* __restrict__ eta, float* __restrict__ ys,
                         float* __restrict__ fwg, float* __restrict__ momg) {
  if (flag[0] == 0) return;
  const int b = blockIdx.x;
  const int tid = threadIdx.x;
  const int wave = tid >> 6, lane = tid & 63;
  float* fw = fwg + (long)b * 262144;
  float* mm = momg + (long)b * 262144;
  for (int e = tid; e < 262144; e += 1024) { fw[e] = base_w[e]; mm[e] = 0.f; }
  __shared__ float xs[512], errs[512], red[16];
  const float* xb = x2 + (long)b * 262144;
  for (int t = 0; t < 512; t++) {
    __syncthreads();
    if (tid < 512) xs[tid] = xb[t * 512 + tid];
    __syncthreads();
    if (tid < 512) {
      float acc = 0.f;
      for (int c = 0; c < 512; c++) acc = fmaf(fw[(long)tid * 512 + c], xs[c], acc);
      const float y = acc + tbias[tid];
      ys[((long)b * 512 + t) * 512 + tid] = y;
      errs[tid] = (y - xs[tid]) * (1.f / 512.f);
    }
    __syncthreads();
    const float eta_t = eta[b * 512 + t];
    float nsq = 0.f;
    for (int e = tid; e < 262144; e += 1024) {
      const int r = e >> 9, c = e & 511;
      const float m2 = fmaf(0.9f, mm[e], 0.1f * errs[r] * xs[c]);
      mm[e] = m2;
      const float f2 = fmaf(-eta_t, m2, fw[e]);
      fw[e] = f2;
      nsq = fmaf(f2, f2, nsq);
    }
    nsq = wave_red_sum64(nsq);
    if (lane == 0) red[wave] = nsq;
    __syncthreads();
    if (tid == 0) {
      float s = 0.f;
      for (int w = 0; w < 16; w++) s += red[w];
      red[0] = s;
    }
    __syncthreads();
    const float norm = fmaxf(sqrtf(red[0]), 1e-6f);
    const float sc = fminf(32.f / norm, 1.f);
    if (sc < 1.f)
      for (int e = tid; e < 262144; e += 1024) fw[e] *= sc;
  }
}

// ------------------------------ host launch ------------------------------
extern "C" void kernel_launch(void* const* d_in, const int* in_sizes, int n_in,
                              void* d_out, int out_size, void* d_ws, size_t ws_size,
                              hipStream_t stream) {
  (void)in_sizes; (void)n_in; (void)out_size;
  const float* x      = (const float*)d_in[0];
  const float* Wq     = (const float*)d_in[1];
  const float* Wk1    = (const float*)d_in[2];
  const float* Wk2    = (const float*)d_in[3];
  const float* Wv     = (const float*)d_in[4];
  const float* Wo     = (const float*)d_in[5];
  const float* lamlog = (const float*)d_in[6];
  const float* ln1g   = (const float*)d_in[7];
  const float* ln1b   = (const float*)d_in[8];
  const float* basew  = (const float*)d_in[9];
  const float* tttb   = (const float*)d_in[10];
  const float* loglr  = (const float*)d_in[11];
  const float* ln2g   = (const float*)d_in[12];
  const float* ln2b   = (const float*)d_in[13];
  const float* W1     = (const float*)d_in[14];
  const float* b1     = (const float*)d_in[15];
  const float* W2     = (const float*)d_in[16];
  const float* b2     = (const float*)d_in[17];
  const float* ln3g   = (const float*)d_in[18];
  const float* ln3b   = (const float*)d_in[19];
  float* out = (float*)d_out;

  char* ws = (char*)d_ws;
  size_t off = 0;
  auto alloc = [&](size_t bytes) {
    size_t o = off;
    off += (bytes + 255) & ~(size_t)255;
    return o;
  };
  f16* WqH   = (f16*)(ws + alloc(262144 * 2));
  f16* Wk1H  = (f16*)(ws + alloc(262144 * 2));
  f16* Wk2H  = (f16*)(ws + alloc(262144 * 2));
  f16* WvH   = (f16*)(ws + alloc(262144 * 2));
  f16* WoH   = (f16*)(ws + alloc(262144 * 2));
  f16* W1H   = (f16*)(ws + alloc(1048576 * 2));
  f16* W2H   = (f16*)(ws + alloc(1048576 * 2));
  (void)Wk1H; (void)Wk2H; (void)WvH; (void)W1H;
  f16* xlnH  = (f16*)(ws + alloc(524288 * 2));
  f16* qh    = (f16*)(ws + alloc(524288 * 2));
  f16* k1h   = (f16*)(ws + alloc(524288 * 2));
  f16* k2h   = (f16*)(ws + alloc(524288 * 2));
  f16* vTh   = (f16*)(ws + alloc(524288 * 2));
  (void)k2h;
  f16* obtd  = (f16*)(ws + alloc(524288 * 2));
  f16* x3h   = (f16*)(ws + alloc(524288 * 2));
  f16* zh    = (f16*)(ws + alloc(2097152 * 2));
  float* h1  = (float*)(ws + alloc(524288 * 4));
  float* x2  = (float*)(ws + alloc(524288 * 4));
  float* ysb = (float*)(ws + alloc(524288 * 4));
  float* h2  = (float*)(ws + alloc(524288 * 4));
  float* eta = (float*)(ws + alloc(1024 * 4));
  float* npt = (float*)(ws + alloc((size_t)512 * 1024 * 4 * 4));  // 8MB norm partials
  float* nvd = (float*)(ws + alloc(524288 * 4));                  // eta diffs
  float* nov = (float*)(ws + alloc(1024 * 4));
  int* flag  = (int*)(ws + alloc(256));
  float* fwfb  = (float*)(ws + alloc(524288 * 4));
  float* momfb = (float*)(ws + alloc(524288 * 4));

  int hc = 16;
  while (hc > 1 && off + (size_t)hc * (262144ull * 4 * 2 + 262144ull * 2) > ws_size) hc >>= 1;
  float* S1  = (float*)(ws + alloc((size_t)hc * 262144 * 4));  // S2 = S1 + hc*262144
  float* S2  = (float*)(ws + alloc((size_t)hc * 262144 * 4));
  f16* attnb = (f16*)(ws + alloc((size_t)hc * 262144 * 2));
  (void)S2;

  // ---- all weight casts in one launch ----
  cvt_all_kernel<<<3328, 256, 0, stream>>>(Wq, Wk1, Wk2, Wv, Wo, W1, W2, WqH);

  // ---- LN1 -> xln (fp16) ----
  ln_kernel<<<256, 256, 0, stream>>>(x, nullptr, ln1g, ln1b, nullptr, nullptr, xlnH);

  // ---- q/k1/k2/vT in one launch (z selects weight + epilogue) ----
  gemm_bt<EPI_QKV><<<dim3(4, 8, 4), 256, 0, stream>>>(
      xlnH, WqH, 512, 512, 0, 262144, qh, nullptr, nullptr, 512, 1.f, 0, 0);

  // ---- attention ----
  const int nc = 16 / hc;
  for (int c = 0; c < nc; c++) {
    const int cs = c * hc;
    gemm_bt<EPI_SCORES><<<dim3(4, 4, 2 * hc), 256, 0, stream>>>(
        qh + (long)cs * 32768, k1h + (long)cs * 32768, 64, 64, 0, 0, S1,
        nullptr, nullptr, 64, 0.125f, 0, hc);
    softmax_diff_kernel<<<hc * 128, 256, 0, stream>>>(S1, S2, lamlog, attnb, cs);
    gemm_bt<EPI_PV><<<dim3(1, 4, hc), 256, 0, stream>>>(
        attnb, vTh + (long)cs * 32768, 512, 512, 262144, 32768, obtd,
        nullptr, nullptr, 512, 1.f, cs, 0);
  }

  // ---- Wo projection + residual -> h1 ----
  gemm_bt<EPI_WO><<<dim3(4, 8, 1), 256, 0, stream>>>(obtd, WoH, 512, 512, 0, 0, h1, nullptr, x, 512, 1.f, 0, 0);

  // ---- LN2 -> x2 (f32) ----
  ln_kernel<<<256, 256, 0, stream>>>(h1, nullptr, ln2g, ln2b, nullptr, x2, nullptr);

  // ---- TTT ----
  hipMemsetAsync(flag, 0, 4, stream);
  eta_diff_kernel<<<16, 64, 0, stream>>>(x2, nvd);
  eta_nov_kernel<<<256, 256, 0, stream>>>(nvd, nov);
  eta_scan_kernel<<<2, 64, 0, stream>>>(nov, loglr, eta);
  ttt_fast_kernel<<<1024, 64, 0, stream>>>(x2, basew, tttb, eta, ysb, npt);
  verify_kernel<<<512, 1024, 0, stream>>>(npt, flag);
  ttt_fallback_kernel<<<2, 1024, 0, stream>>>(flag, x2, basew, tttb, eta, ysb, fwfb, momfb);

  // ---- h2 = h1 + ys ; LN3 -> x3 (fp16) ----
  ln_kernel<<<256, 256, 0, stream>>>(h1, ysb, ln3g, ln3b, h2, nullptr, x3h);

  // ---- FFN ----
  gemm_bt<EPI_GELU><<<dim3(16, 8, 1), 256, 0, stream>>>(x3h, W1H, 512, 512, 0, 0, zh, b1, nullptr, 512, 1.f, 0, 0);
  gemm_bt<EPI_OUT><<<dim3(4, 8, 1), 256, 0, stream>>>(zh, W2H, 2048, 2048, 0, 0, out, b2, h2, 2048, 1.f, 0, 0);
}